// Round 4
// baseline (388.014 us; speedup 1.0000x reference)
//
#include <hip/hip_runtime.h>
#include <stdint.h>

#define N_NODES 50000
#define N_EDGES 800000
#define FEAT    128
#define NGRAPH  64

#define E_BLKS    3125   // 800000 edges / 256
#define GEMM_BLKS 6250   // (N/16) m-tiles * 8 n-tiles / 4 waves
#define GR_BLKS   (GEMM_BLKS + E_BLKS)   // 9375, roles interleaved 2:1

typedef __attribute__((ext_vector_type(8))) short short8;
typedef __attribute__((ext_vector_type(4))) float floatx4;

static __device__ __forceinline__ ushort f2bf(float f) {
  uint32_t x = __float_as_uint(f);
  x += 0x7FFF + ((x >> 16) & 1);   // RNE
  return (ushort)(x >> 16);
}
static __device__ __forceinline__ float bfLo(uint32_t u) {
  return __uint_as_float(u << 16);
}
static __device__ __forceinline__ float bfHi(uint32_t u) {
  return __uint_as_float(u & 0xFFFF0000u);
}

// cvt + transpose: in is row-major [128][128] fp32 [k][n], out is [n][k] bf16
static __device__ __forceinline__ void cvt4T(const float* __restrict__ in,
                                             ushort* __restrict__ outT, int i) {
  float4 v = ((const float4*)in)[i];
  int k = (4 * i) >> 7;          // row
  int n = (4 * i) & 127;         // col
  outT[(size_t)(n + 0) * FEAT + k] = f2bf(v.x);
  outT[(size_t)(n + 1) * FEAT + k] = f2bf(v.y);
  outT[(size_t)(n + 2) * FEAT + k] = f2bf(v.z);
  outT[(size_t)(n + 3) * FEAT + k] = f2bf(v.w);
}

// ---- tiny: transpose-cvt both conv weights (runs before gemm_rank) ------
__global__ __launch_bounds__(256) void wcvt(const float* __restrict__ w0,
                                            const float* __restrict__ w1,
                                            ushort* __restrict__ wbT) {
  int i = blockIdx.x * 256 + threadIdx.x;   // 0..8191
  if (i < 4096) cvt4T(w0, wbT, i);
  else cvt4T(w1, wbT + FEAT * FEAT, i - 4096);
}

// ---- gemm body, A from fp32 (in-register cvt), B from bf16 W^T ----------
static __device__ __forceinline__ void gemm_body_f32a(int wave, int lane,
                                                      const float* __restrict__ X,
                                                      const ushort* __restrict__ WT,
                                                      ushort* __restrict__ XW) {
  int mt = wave >> 3;  // 8 n-tiles per m-tile
  int nt = wave & 7;
  int m0 = mt * 16, n0 = nt * 16;
  int r = lane & 15, quad = lane >> 4;
  floatx4 acc = {0.f, 0.f, 0.f, 0.f};
  const float* xrow = X + (size_t)(m0 + r) * FEAT;
  const ushort* wrow = WT + (size_t)(n0 + r) * FEAT;
#pragma unroll
  for (int kb = 0; kb < 4; ++kb) {
    int k0 = kb * 32 + quad * 8;
    float4 f0 = *(const float4*)(xrow + k0);
    float4 f1 = *(const float4*)(xrow + k0 + 4);
    short8 a;
    a[0] = (short)f2bf(f0.x); a[1] = (short)f2bf(f0.y);
    a[2] = (short)f2bf(f0.z); a[3] = (short)f2bf(f0.w);
    a[4] = (short)f2bf(f1.x); a[5] = (short)f2bf(f1.y);
    a[6] = (short)f2bf(f1.z); a[7] = (short)f2bf(f1.w);
    short8 b = *(const short8*)(wrow + k0);
    acc = __builtin_amdgcn_mfma_f32_16x16x32_bf16(a, b, acc, 0, 0, 0);
  }
#pragma unroll
  for (int reg = 0; reg < 4; ++reg) {
    int row = quad * 4 + reg;
    XW[(size_t)(m0 + row) * FEAT + n0 + r] = f2bf(acc[reg]);
  }
}

// ---- K1: conv1 gemm interleaved 2:1 with the rank-atomic pass -----------
__global__ __launch_bounds__(256) void gemm_rank(const float* __restrict__ x,
                                                 const ushort* __restrict__ wbT,
                                                 ushort* __restrict__ msl,
                                                 const int* __restrict__ dst,
                                                 int* __restrict__ cnt,
                                                 int* __restrict__ rank) {
  int b = blockIdx.x, t = threadIdx.x;
  int third = b / 3;
  int rem = b - third * 3;
  if (rem < 2) {
    int gb = third * 2 + rem;                  // 0..6249
    gemm_body_f32a(gb * 4 + (t >> 6), t & 63, x, wbT, msl);
  } else {
    int e = third * 256 + t;                   // 0..799999 exactly
    rank[e] = atomicAdd(&cnt[dst[e]], 1);
  }
}

// ---- fused: dinv + graph counts + scan1 (all read cnt) ------------------
__global__ __launch_bounds__(256) void dinv_scan1(const int* __restrict__ cnt,
                                                  const int* __restrict__ batch,
                                                  float* __restrict__ dinv,
                                                  float* __restrict__ cnt_g,
                                                  int* __restrict__ ptr,
                                                  int* __restrict__ bsums) {
  __shared__ int tmp[256];
  __shared__ int bins[NGRAPH];
  if (threadIdx.x < NGRAPH) bins[threadIdx.x] = 0;
  int i = blockIdx.x * 256 + threadIdx.x;
  int v = (i < N_NODES) ? cnt[i] : 0;
  tmp[threadIdx.x] = v;
  __syncthreads();
  for (int off = 1; off < 256; off <<= 1) {
    int t = (threadIdx.x >= off) ? tmp[threadIdx.x - off] : 0;
    __syncthreads();
    tmp[threadIdx.x] += t;
    __syncthreads();
  }
  if (i < N_NODES) ptr[i] = tmp[threadIdx.x] - v;           // exclusive
  if (threadIdx.x == 255) bsums[blockIdx.x] = tmp[255];
  if (i < N_NODES) {
    dinv[i] = rsqrtf((float)v + 1.0f);
    atomicAdd(&bins[batch[i]], 1);
  }
  __syncthreads();
  if (threadIdx.x < NGRAPH && bins[threadIdx.x] > 0)
    atomicAdd(&cnt_g[threadIdx.x], (float)bins[threadIdx.x]);
}

__global__ __launch_bounds__(256) void scan2(int* __restrict__ bsums, int nb) {
  __shared__ int tmp[256];
  int v = (threadIdx.x < nb) ? bsums[threadIdx.x] : 0;
  tmp[threadIdx.x] = v;
  __syncthreads();
  for (int off = 1; off < 256; off <<= 1) {
    int t = (threadIdx.x >= off) ? tmp[threadIdx.x - off] : 0;
    __syncthreads();
    tmp[threadIdx.x] += t;
    __syncthreads();
  }
  if (threadIdx.x < nb) bsums[threadIdx.x] = tmp[threadIdx.x] - v;  // exclusive
}

__global__ __launch_bounds__(256) void scan3(int* __restrict__ ptr,
                                             const int* __restrict__ bsums) {
  int i = blockIdx.x * 256 + threadIdx.x;
  if (i < N_NODES) ptr[i] += bsums[blockIdx.x];
}

// ---- fill: atomic-free CSR scatter, payload {src, dinv[src]} ------------
__global__ __launch_bounds__(256) void fill_csr(const int* __restrict__ src,
                                                const int* __restrict__ dst,
                                                const int* __restrict__ rank,
                                                const int* __restrict__ ptr,
                                                const float* __restrict__ dinv,
                                                int2* __restrict__ edges) {
  int e = blockIdx.x * 256 + threadIdx.x;
  if (e >= N_EDGES) return;
  int s = src[e];
  edges[ptr[dst[e]] + rank[e]] = make_int2(s, __float_as_int(dinv[s]));
}

// ---- conv2 gemm: bf16 A x bf16 W^T ---------------------------------------
__global__ __launch_bounds__(256) void gemm128(const ushort* __restrict__ X,
                                               const ushort* __restrict__ WT,
                                               ushort* __restrict__ XW) {
  int wave = (blockIdx.x * 256 + threadIdx.x) >> 6;
  int lane = threadIdx.x & 63;
  int mt = wave >> 3;
  int nt = wave & 7;
  int m0 = mt * 16, n0 = nt * 16;
  int r = lane & 15, quad = lane >> 4;
  floatx4 acc = {0.f, 0.f, 0.f, 0.f};
  const ushort* xrow = X + (size_t)(m0 + r) * FEAT;
  const ushort* wrow = WT + (size_t)(n0 + r) * FEAT;
#pragma unroll
  for (int kb = 0; kb < 4; ++kb) {
    int k0 = kb * 32 + quad * 8;
    short8 a = *(const short8*)(xrow + k0);
    short8 b = *(const short8*)(wrow + k0);
    acc = __builtin_amdgcn_mfma_f32_16x16x32_bf16(a, b, acc, 0, 0, 0);
  }
#pragma unroll
  for (int reg = 0; reg < 4; ++reg) {
    int row = quad * 4 + reg;
    XW[(size_t)(m0 + row) * FEAT + n0 + r] = f2bf(acc[reg]);
  }
}

// ---------------- aggregation: wave/node, 8-edge ILP, per-edge dinv_s ----
// MODE 0: out bf16 = relu(di*acc + b)   (conv1/conv2)
// MODE 2: out fp32 = di*acc             (conv3 pre-pool, no bias)
template <int MODE>
__global__ __launch_bounds__(256) void agg_kernel(const ushort* __restrict__ msg,
                                                  const float* __restrict__ dinv,
                                                  const int* __restrict__ ptr,
                                                  const int* __restrict__ cnt,
                                                  const int2* __restrict__ edges,
                                                  const float* __restrict__ bias,
                                                  void* __restrict__ outp) {
  int wave = (blockIdx.x * 256 + threadIdx.x) >> 6;
  int lane = threadIdx.x & 63;
  if (wave >= N_NODES) return;
  int v = wave;
  float di = dinv[v];
  const uint32_t* m32 = (const uint32_t*)msg;   // 64 dwords per node row
  uint32_t su = m32[(size_t)v * 64 + lane];     // self term, weight di
  float ax0 = di * bfLo(su), ay0 = di * bfHi(su);
  float ax1 = 0.f, ay1 = 0.f, ax2 = 0.f, ay2 = 0.f, ax3 = 0.f, ay3 = 0.f;
  int start = ptr[v];
  int n = cnt[v];
  int i = 0;
  if ((start & 1) && n > 0) {                   // align to int4 (2-edge) bound
    int2 e = edges[start];
    uint32_t u = m32[(size_t)e.x * 64 + lane];
    float nrm = __int_as_float(e.y);
    ax0 = fmaf(nrm, bfLo(u), ax0);
    ay0 = fmaf(nrm, bfHi(u), ay0);
    i = 1;
  }
  for (; i + 8 <= n; i += 8) {
    const int4* ep = (const int4*)(edges + start + i);   // 16B-aligned
    int4 q0 = ep[0], q1 = ep[1], q2 = ep[2], q3 = ep[3];
    uint32_t u0 = m32[(size_t)q0.x * 64 + lane];
    uint32_t u1 = m32[(size_t)q0.z * 64 + lane];
    uint32_t u2 = m32[(size_t)q1.x * 64 + lane];
    uint32_t u3 = m32[(size_t)q1.z * 64 + lane];
    uint32_t u4 = m32[(size_t)q2.x * 64 + lane];
    uint32_t u5 = m32[(size_t)q2.z * 64 + lane];
    uint32_t u6 = m32[(size_t)q3.x * 64 + lane];
    uint32_t u7 = m32[(size_t)q3.z * 64 + lane];
    float n0 = __int_as_float(q0.y), n1 = __int_as_float(q0.w);
    float n2 = __int_as_float(q1.y), n3 = __int_as_float(q1.w);
    float n4 = __int_as_float(q2.y), n5 = __int_as_float(q2.w);
    float n6 = __int_as_float(q3.y), n7 = __int_as_float(q3.w);
    ax0 = fmaf(n0, bfLo(u0), ax0); ay0 = fmaf(n0, bfHi(u0), ay0);
    ax1 = fmaf(n1, bfLo(u1), ax1); ay1 = fmaf(n1, bfHi(u1), ay1);
    ax2 = fmaf(n2, bfLo(u2), ax2); ay2 = fmaf(n2, bfHi(u2), ay2);
    ax3 = fmaf(n3, bfLo(u3), ax3); ay3 = fmaf(n3, bfHi(u3), ay3);
    ax0 = fmaf(n4, bfLo(u4), ax0); ay0 = fmaf(n4, bfHi(u4), ay0);
    ax1 = fmaf(n5, bfLo(u5), ax1); ay1 = fmaf(n5, bfHi(u5), ay1);
    ax2 = fmaf(n6, bfLo(u6), ax2); ay2 = fmaf(n6, bfHi(u6), ay2);
    ax3 = fmaf(n7, bfLo(u7), ax3); ay3 = fmaf(n7, bfHi(u7), ay3);
  }
  for (; i < n; ++i) {
    int2 e = edges[start + i];
    float nrm = __int_as_float(e.y);
    uint32_t u = m32[(size_t)e.x * 64 + lane];
    ax0 = fmaf(nrm, bfLo(u), ax0);
    ay0 = fmaf(nrm, bfHi(u), ay0);
  }
  float ax = (ax0 + ax1) + (ax2 + ax3);
  float ay = (ay0 + ay1) + (ay2 + ay3);
  if (MODE == 2) {
    ((float2*)outp)[(size_t)v * 64 + lane] = make_float2(ax * di, ay * di);
  } else {
    ax = fmaf(ax, di, bias[2 * lane]);
    ay = fmaf(ay, di, bias[2 * lane + 1]);
    ax = fmaxf(ax, 0.f);
    ay = fmaxf(ay, 0.f);
    ushort2 h2;
    h2.x = f2bf(ax);
    h2.y = f2bf(ay);
    ((ushort2*)outp)[(size_t)v * 64 + lane] = h2;
  }
}

// ---------------- pool: segment-sum a3 over batch-sorted nodes -----------
__global__ __launch_bounds__(256) void pool_sum(const float* __restrict__ a3,
                                                const int* __restrict__ batch,
                                                float* __restrict__ P) {
  int wave = blockIdx.x * 4 + (threadIdx.x >> 6);
  int lane = threadIdx.x & 63;
  int v0 = wave * 16;
  if (v0 >= N_NODES) return;
  int vend = v0 + 16;
  if (vend > N_NODES) vend = N_NODES;
  const float2* a2 = (const float2*)a3;
  float ax = 0.f, ay = 0.f;
  int g = batch[v0];
  for (int v = v0; v < vend; ++v) {
    int gv = batch[v];
    if (gv != g) {
      atomicAdd(&P[(size_t)g * FEAT + 2 * lane], ax);
      atomicAdd(&P[(size_t)g * FEAT + 2 * lane + 1], ay);
      ax = 0.f; ay = 0.f; g = gv;
    }
    float2 t = a2[(size_t)v * 64 + lane];
    ax += t.x;
    ay += t.y;
  }
  atomicAdd(&P[(size_t)g * FEAT + 2 * lane], ax);
  atomicAdd(&P[(size_t)g * FEAT + 2 * lane + 1], ay);
}

// ---------------- fused head ---------------------------------------------
// head_layer4: thread owns 4 consecutive output cols (one float4 weight
// load per k), 4 independent acc sets -> 4x fewer dependent load rounds
// than the scalar version. Requires C%4==0 and (K/parts)%4==0.
__device__ __forceinline__ void head_layer4(const float* __restrict__ IN,
                                            float* __restrict__ OUT,
                                            const float* __restrict__ w,
                                            const float* __restrict__ b,
                                            int K, int C, int relu,
                                            float* __restrict__ gout, int t) {
  int nc4 = C >> 2;                  // float4 columns
  int parts = 1024 / nc4;
  int part = t / nc4;
  int c4 = t - part * nc4;
  int kchunk = K / parts;
  if (t < C) OUT[t] = b[t];
  __syncthreads();
  int k0 = part * kchunk;
  float4 a0 = make_float4(0.f, 0.f, 0.f, 0.f);
  float4 a1 = make_float4(0.f, 0.f, 0.f, 0.f);
  float4 a2 = make_float4(0.f, 0.f, 0.f, 0.f);
  float4 a3 = make_float4(0.f, 0.f, 0.f, 0.f);
  const float4* wp = (const float4*)w + (size_t)k0 * nc4 + c4;
#pragma unroll 2
  for (int k = 0; k < kchunk; k += 4) {
    float4 w0 = wp[(size_t)(k + 0) * nc4];
    float4 w1 = wp[(size_t)(k + 1) * nc4];
    float4 w2 = wp[(size_t)(k + 2) * nc4];
    float4 w3 = wp[(size_t)(k + 3) * nc4];
    float i0 = IN[k0 + k], i1 = IN[k0 + k + 1];
    float i2 = IN[k0 + k + 2], i3 = IN[k0 + k + 3];
    a0.x = fmaf(i0, w0.x, a0.x); a0.y = fmaf(i0, w0.y, a0.y);
    a0.z = fmaf(i0, w0.z, a0.z); a0.w = fmaf(i0, w0.w, a0.w);
    a1.x = fmaf(i1, w1.x, a1.x); a1.y = fmaf(i1, w1.y, a1.y);
    a1.z = fmaf(i1, w1.z, a1.z); a1.w = fmaf(i1, w1.w, a1.w);
    a2.x = fmaf(i2, w2.x, a2.x); a2.y = fmaf(i2, w2.y, a2.y);
    a2.z = fmaf(i2, w2.z, a2.z); a2.w = fmaf(i2, w2.w, a2.w);
    a3.x = fmaf(i3, w3.x, a3.x); a3.y = fmaf(i3, w3.y, a3.y);
    a3.z = fmaf(i3, w3.z, a3.z); a3.w = fmaf(i3, w3.w, a3.w);
  }
  atomicAdd(&OUT[4 * c4 + 0], (a0.x + a1.x) + (a2.x + a3.x));
  atomicAdd(&OUT[4 * c4 + 1], (a0.y + a1.y) + (a2.y + a3.y));
  atomicAdd(&OUT[4 * c4 + 2], (a0.z + a1.z) + (a2.z + a3.z));
  atomicAdd(&OUT[4 * c4 + 3], (a0.w + a1.w) + (a2.w + a3.w));
  __syncthreads();
  if (t < C) {
    float v = OUT[t];
    if (relu) { v = fmaxf(v, 0.f); OUT[t] = v; }
    if (gout) gout[t] = v;
  }
  __syncthreads();
}

// scalar path (fc5: C=10)
__device__ __forceinline__ void head_layer(const float* __restrict__ IN,
                                           float* __restrict__ OUT,
                                           const float* __restrict__ w,
                                           const float* __restrict__ b,
                                           int K, int C, int Cp, int relu,
                                           float* __restrict__ gout, int t) {
  int parts = 1024 / Cp;
  int part = t / Cp;
  int c = t - part * Cp;
  int kchunk = K / parts;
  if (t < C) OUT[t] = b[t];
  __syncthreads();
  if (c < C) {
    int k0 = part * kchunk;
    float a0 = 0.f;
    const float* wp = w + (size_t)k0 * C + c;
    for (int k = 0; k < kchunk; ++k)
      a0 = fmaf(IN[k0 + k], wp[(size_t)k * C], a0);
    atomicAdd(&OUT[c], a0);
  }
  __syncthreads();
  if (t < C) {
    float v = OUT[t];
    if (relu) { v = fmaxf(v, 0.f); OUT[t] = v; }
    if (gout) gout[t] = v;
  }
  __syncthreads();
}

__global__ __launch_bounds__(1024) void fc_head(const float* __restrict__ P,
                                                const float* __restrict__ cnt_g,
                                                const float* __restrict__ w3,
                                                const float* __restrict__ b3,
                                                const float* __restrict__ w1,
                                                const float* __restrict__ b1,
                                                const float* __restrict__ w2,
                                                const float* __restrict__ b2,
                                                const float* __restrict__ wf3,
                                                const float* __restrict__ bf3,
                                                const float* __restrict__ w4,
                                                const float* __restrict__ b4,
                                                const float* __restrict__ w5,
                                                const float* __restrict__ b5,
                                                float* __restrict__ out_f,
                                                float* __restrict__ out_y) {
  __shared__ float A[1024];
  __shared__ float B[1024];
  int r = blockIdx.x, t = threadIdx.x;
  if (t < FEAT) A[t] = P[r * FEAT + t] / fmaxf(cnt_g[r], 1.0f);   // Pn
  __syncthreads();
  head_layer4(A, B, w3, b3, 128, 128, 0, out_f + (size_t)r * FEAT, t);
  head_layer4(B, A, w1, b1, 128, 1024, 1, nullptr, t);
  head_layer4(A, B, w2, b2, 1024, 512, 1, nullptr, t);
  head_layer4(B, A, wf3, bf3, 512, 256, 1, nullptr, t);
  head_layer4(A, B, w4, b4, 256, 128, 1, nullptr, t);
  head_layer(B, A, w5, b5, 128, 10, 16, 0, out_y + (size_t)r * 10, t);
}

// =========================================================================
extern "C" void kernel_launch(void* const* d_in, const int* in_sizes, int n_in,
                              void* d_out, int out_size, void* d_ws, size_t ws_size,
                              hipStream_t stream) {
  const float* x         = (const float*)d_in[0];
  const int*   ei        = (const int*)d_in[1];     // [2][E]: row0 src, row1 dst
  const int*   batch     = (const int*)d_in[2];
  const float* conv_w[3] = {(const float*)d_in[3], (const float*)d_in[5], (const float*)d_in[7]};
  const float* conv_b[3] = {(const float*)d_in[4], (const float*)d_in[6], (const float*)d_in[8]};
  const float* fc_w[5]   = {(const float*)d_in[9],  (const float*)d_in[11],
                            (const float*)d_in[13], (const float*)d_in[15],
                            (const float*)d_in[17]};
  const float* fc_b[5]   = {(const float*)d_in[10], (const float*)d_in[12],
                            (const float*)d_in[14], (const float*)d_in[16],
                            (const float*)d_in[18]};
  const int* e_src = ei;
  const int* e_dst = ei + N_EDGES;
  float* out_f = (float*)d_out;                  // [64][128] fp32  (output 0)
  float* out_y = (float*)d_out + NGRAPH * FEAT;  // [64][10]  fp32  (output 1)

  char* p = (char*)d_ws;
  auto carve = [&](size_t bytes) {
    char* r = p;
    p += (bytes + 255) & ~(size_t)255;
    return r;
  };
  int*    cnt_i   = (int*)carve(N_NODES * 4);
  float*  dinv    = (float*)carve(N_NODES * 4);
  int*    csr_ptr = (int*)carve(N_NODES * 4);
  int*    bsums   = (int*)carve(256 * 4);
  int2*   edges   = (int2*)carve((size_t)N_EDGES * 8);            // {src, dinv_s}
  ushort* wbT     = (ushort*)carve((size_t)2 * FEAT * FEAT * 2);  // bf16 W^T conv1/2
  ushort* hbuf    = (ushort*)carve((size_t)N_NODES * FEAT * 2);   // bf16 h
  float*  f_sum   = (float*)carve(NGRAPH * FEAT * 4);             // P
  float*  cnt_g   = (float*)carve(NGRAPH * 4);                    // adjacent to f_sum
  // Shared region (25.6 MB): rank (3.2M) + msl (12.8M) live early; a3 (fp32
  // [N][128]) overlays the whole region. rank dead after fill_csr; msl dead
  // after each agg<0> reads it; a3 written by agg<2> which reads only
  // hbuf/edges/ptr/cnt -> no overlap hazard.
  char*   region  = carve((size_t)N_NODES * FEAT * 4);
  int*    rank    = (int*)region;
  ushort* msl     = (ushort*)(region + (size_t)N_EDGES * 4);
  float*  a3      = (float*)region;

  const int BLK_N = (N_NODES + 255) / 256;   // 196

  // zero-init (ws + out are poisoned 0xAA each timed call)
  hipMemsetAsync(cnt_i, 0, N_NODES * 4, stream);
  hipMemsetAsync(f_sum, 0, NGRAPH * FEAT * 4 + 256, stream);      // f_sum + cnt_g

  // ---- tiny weight transpose-cvt (feeds gemm_rank) ----
  wcvt<<<32, 256, 0, stream>>>(conv_w[0], conv_w[1], wbT);

  // ---- K1: conv1 gemm (fp32 A, in-reg cvt) overlapped with rank atomics --
  gemm_rank<<<GR_BLKS, 256, 0, stream>>>(x, wbT, msl, e_dst, cnt_i, rank);

  // ---- dinv + graph counts + scan1 (1 dispatch) ----
  dinv_scan1<<<BLK_N, 256, 0, stream>>>(cnt_i, batch, dinv, cnt_g, csr_ptr, bsums);
  scan2<<<1, 256, 0, stream>>>(bsums, BLK_N);
  scan3<<<BLK_N, 256, 0, stream>>>(csr_ptr, bsums);

  // ---- atomic-free CSR fill ----
  fill_csr<<<E_BLKS, 256, 0, stream>>>(e_src, e_dst, rank, csr_ptr, dinv, edges);

  const int AGG_BLKS  = (N_NODES + 3) / 4;
  const int POOL_BLKS = (N_NODES / 16 + 3) / 4 + 1;

  // ---- conv1 agg: h1 = relu(di*acc + b1) ----
  agg_kernel<0><<<AGG_BLKS, 256, 0, stream>>>(msl, dinv, csr_ptr, cnt_i, edges,
                                              conv_b[0], hbuf);
  // ---- conv2: msg2 = h1 W2; h2 = relu(di*acc + b2) ----
  gemm128<<<GEMM_BLKS, 256, 0, stream>>>(hbuf, wbT + FEAT * FEAT, msl);
  agg_kernel<0><<<AGG_BLKS, 256, 0, stream>>>(msl, dinv, csr_ptr, cnt_i, edges,
                                              conv_b[1], hbuf);
  // ---- conv3 pre-pool: a3 = di*acc(h2), fp32 ----
  agg_kernel<2><<<AGG_BLKS, 256, 0, stream>>>(hbuf, dinv, csr_ptr, cnt_i, edges,
                                              nullptr, a3);
  // ---- per-graph segment sum (batch sorted) ----
  pool_sum<<<POOL_BLKS, 256, 0, stream>>>(a3, batch, f_sum);

  // ---- fused head: Pn -> W3 -> fc1..fc5 (one launch) ----
  fc_head<<<NGRAPH, 1024, 0, stream>>>(f_sum, cnt_g, conv_w[2], conv_b[2],
                                       fc_w[0], fc_b[0], fc_w[1], fc_b[1],
                                       fc_w[2], fc_b[2], fc_w[3], fc_b[3],
                                       fc_w[4], fc_b[4], out_f, out_y);
}

// Round 5
// 375.042 us; speedup vs baseline: 1.0346x; 1.0346x over previous
//
#include <hip/hip_runtime.h>
#include <stdint.h>

#define N_NODES 50000
#define N_EDGES 800000
#define FEAT    128
#define NGRAPH  64

#define E_BLKS    3125   // 800000 edges / 256
#define GEMM_BLKS 6250   // (N/16) m-tiles * 8 n-tiles / 4 waves
#define GR_BLKS   (GEMM_BLKS + E_BLKS)   // 9375, roles interleaved 2:1

typedef __attribute__((ext_vector_type(8))) short short8;
typedef __attribute__((ext_vector_type(4))) float floatx4;

static __device__ __forceinline__ ushort f2bf(float f) {
  uint32_t x = __float_as_uint(f);
  x += 0x7FFF + ((x >> 16) & 1);   // RNE
  return (ushort)(x >> 16);
}
static __device__ __forceinline__ float bfLo(uint32_t u) {
  return __uint_as_float(u << 16);
}
static __device__ __forceinline__ float bfHi(uint32_t u) {
  return __uint_as_float(u & 0xFFFF0000u);
}

// cvt + transpose: in is row-major [128][128] fp32 [k][n], out is [n][k] bf16
static __device__ __forceinline__ void cvt4T(const float* __restrict__ in,
                                             ushort* __restrict__ outT, int i) {
  float4 v = ((const float4*)in)[i];
  int k = (4 * i) >> 7;          // row
  int n = (4 * i) & 127;         // col
  outT[(size_t)(n + 0) * FEAT + k] = f2bf(v.x);
  outT[(size_t)(n + 1) * FEAT + k] = f2bf(v.y);
  outT[(size_t)(n + 2) * FEAT + k] = f2bf(v.z);
  outT[(size_t)(n + 3) * FEAT + k] = f2bf(v.w);
}

// ---- tiny: transpose-cvt both conv weights (runs before gemm_rank) ------
__global__ __launch_bounds__(256) void wcvt(const float* __restrict__ w0,
                                            const float* __restrict__ w1,
                                            ushort* __restrict__ wbT) {
  int i = blockIdx.x * 256 + threadIdx.x;   // 0..8191
  if (i < 4096) cvt4T(w0, wbT, i);
  else cvt4T(w1, wbT + FEAT * FEAT, i - 4096);
}

// ---- gemm body, A from fp32 (in-register cvt), B from bf16 W^T ----------
static __device__ __forceinline__ void gemm_body_f32a(int wave, int lane,
                                                      const float* __restrict__ X,
                                                      const ushort* __restrict__ WT,
                                                      ushort* __restrict__ XW) {
  int mt = wave >> 3;  // 8 n-tiles per m-tile
  int nt = wave & 7;
  int m0 = mt * 16, n0 = nt * 16;
  int r = lane & 15, quad = lane >> 4;
  floatx4 acc = {0.f, 0.f, 0.f, 0.f};
  const float* xrow = X + (size_t)(m0 + r) * FEAT;
  const ushort* wrow = WT + (size_t)(n0 + r) * FEAT;
#pragma unroll
  for (int kb = 0; kb < 4; ++kb) {
    int k0 = kb * 32 + quad * 8;
    float4 f0 = *(const float4*)(xrow + k0);
    float4 f1 = *(const float4*)(xrow + k0 + 4);
    short8 a;
    a[0] = (short)f2bf(f0.x); a[1] = (short)f2bf(f0.y);
    a[2] = (short)f2bf(f0.z); a[3] = (short)f2bf(f0.w);
    a[4] = (short)f2bf(f1.x); a[5] = (short)f2bf(f1.y);
    a[6] = (short)f2bf(f1.z); a[7] = (short)f2bf(f1.w);
    short8 b = *(const short8*)(wrow + k0);
    acc = __builtin_amdgcn_mfma_f32_16x16x32_bf16(a, b, acc, 0, 0, 0);
  }
#pragma unroll
  for (int reg = 0; reg < 4; ++reg) {
    int row = quad * 4 + reg;
    XW[(size_t)(m0 + row) * FEAT + n0 + r] = f2bf(acc[reg]);
  }
}

// ---- K1: conv1 gemm interleaved 2:1 with the rank-atomic pass -----------
__global__ __launch_bounds__(256) void gemm_rank(const float* __restrict__ x,
                                                 const ushort* __restrict__ wbT,
                                                 ushort* __restrict__ msl,
                                                 const int* __restrict__ dst,
                                                 int* __restrict__ cnt,
                                                 int* __restrict__ rank) {
  int b = blockIdx.x, t = threadIdx.x;
  int third = b / 3;
  int rem = b - third * 3;
  if (rem < 2) {
    int gb = third * 2 + rem;                  // 0..6249
    gemm_body_f32a(gb * 4 + (t >> 6), t & 63, x, wbT, msl);
  } else {
    int e = third * 256 + t;                   // 0..799999 exactly
    rank[e] = atomicAdd(&cnt[dst[e]], 1);
  }
}

// ---- fused: dinv + graph counts + scan1 (all read cnt) ------------------
__global__ __launch_bounds__(256) void dinv_scan1(const int* __restrict__ cnt,
                                                  const int* __restrict__ batch,
                                                  float* __restrict__ dinv,
                                                  float* __restrict__ cnt_g,
                                                  int* __restrict__ ptr,
                                                  int* __restrict__ bsums) {
  __shared__ int tmp[256];
  __shared__ int bins[NGRAPH];
  if (threadIdx.x < NGRAPH) bins[threadIdx.x] = 0;
  int i = blockIdx.x * 256 + threadIdx.x;
  int v = (i < N_NODES) ? cnt[i] : 0;
  tmp[threadIdx.x] = v;
  __syncthreads();
  for (int off = 1; off < 256; off <<= 1) {
    int t = (threadIdx.x >= off) ? tmp[threadIdx.x - off] : 0;
    __syncthreads();
    tmp[threadIdx.x] += t;
    __syncthreads();
  }
  if (i < N_NODES) ptr[i] = tmp[threadIdx.x] - v;           // exclusive
  if (threadIdx.x == 255) bsums[blockIdx.x] = tmp[255];
  if (i < N_NODES) {
    dinv[i] = rsqrtf((float)v + 1.0f);
    atomicAdd(&bins[batch[i]], 1);
  }
  __syncthreads();
  if (threadIdx.x < NGRAPH && bins[threadIdx.x] > 0)
    atomicAdd(&cnt_g[threadIdx.x], (float)bins[threadIdx.x]);
}

__global__ __launch_bounds__(256) void scan2(int* __restrict__ bsums, int nb) {
  __shared__ int tmp[256];
  int v = (threadIdx.x < nb) ? bsums[threadIdx.x] : 0;
  tmp[threadIdx.x] = v;
  __syncthreads();
  for (int off = 1; off < 256; off <<= 1) {
    int t = (threadIdx.x >= off) ? tmp[threadIdx.x - off] : 0;
    __syncthreads();
    tmp[threadIdx.x] += t;
    __syncthreads();
  }
  if (threadIdx.x < nb) bsums[threadIdx.x] = tmp[threadIdx.x] - v;  // exclusive
}

__global__ __launch_bounds__(256) void scan3(int* __restrict__ ptr,
                                             const int* __restrict__ bsums) {
  int i = blockIdx.x * 256 + threadIdx.x;
  if (i < N_NODES) ptr[i] += bsums[blockIdx.x];
}

// ---- fill: atomic-free CSR scatter, payload {src, dinv[src]} ------------
__global__ __launch_bounds__(256) void fill_csr(const int* __restrict__ src,
                                                const int* __restrict__ dst,
                                                const int* __restrict__ rank,
                                                const int* __restrict__ ptr,
                                                const float* __restrict__ dinv,
                                                int2* __restrict__ edges) {
  int e = blockIdx.x * 256 + threadIdx.x;
  if (e >= N_EDGES) return;
  int s = src[e];
  edges[ptr[dst[e]] + rank[e]] = make_int2(s, __float_as_int(dinv[s]));
}

// ---- conv2 gemm: bf16 A x bf16 W^T ---------------------------------------
__global__ __launch_bounds__(256) void gemm128(const ushort* __restrict__ X,
                                               const ushort* __restrict__ WT,
                                               ushort* __restrict__ XW) {
  int wave = (blockIdx.x * 256 + threadIdx.x) >> 6;
  int lane = threadIdx.x & 63;
  int mt = wave >> 3;
  int nt = wave & 7;
  int m0 = mt * 16, n0 = nt * 16;
  int r = lane & 15, quad = lane >> 4;
  floatx4 acc = {0.f, 0.f, 0.f, 0.f};
  const ushort* xrow = X + (size_t)(m0 + r) * FEAT;
  const ushort* wrow = WT + (size_t)(n0 + r) * FEAT;
#pragma unroll
  for (int kb = 0; kb < 4; ++kb) {
    int k0 = kb * 32 + quad * 8;
    short8 a = *(const short8*)(xrow + k0);
    short8 b = *(const short8*)(wrow + k0);
    acc = __builtin_amdgcn_mfma_f32_16x16x32_bf16(a, b, acc, 0, 0, 0);
  }
#pragma unroll
  for (int reg = 0; reg < 4; ++reg) {
    int row = quad * 4 + reg;
    XW[(size_t)(m0 + row) * FEAT + n0 + r] = f2bf(acc[reg]);
  }
}

// ---------------- aggregation: wave/node, 8-edge ILP, per-edge dinv_s ----
// MODE 0: out bf16 = relu(di*acc + b)   (conv1/conv2)
// MODE 2: out fp32 = di*acc             (conv3 pre-pool, no bias)
template <int MODE>
__global__ __launch_bounds__(256) void agg_kernel(const ushort* __restrict__ msg,
                                                  const float* __restrict__ dinv,
                                                  const int* __restrict__ ptr,
                                                  const int* __restrict__ cnt,
                                                  const int2* __restrict__ edges,
                                                  const float* __restrict__ bias,
                                                  void* __restrict__ outp) {
  int wave = (blockIdx.x * 256 + threadIdx.x) >> 6;
  int lane = threadIdx.x & 63;
  if (wave >= N_NODES) return;
  int v = wave;
  float di = dinv[v];
  const uint32_t* m32 = (const uint32_t*)msg;   // 64 dwords per node row
  uint32_t su = m32[(size_t)v * 64 + lane];     // self term, weight di
  float ax0 = di * bfLo(su), ay0 = di * bfHi(su);
  float ax1 = 0.f, ay1 = 0.f, ax2 = 0.f, ay2 = 0.f, ax3 = 0.f, ay3 = 0.f;
  int start = ptr[v];
  int n = cnt[v];
  int i = 0;
  if ((start & 1) && n > 0) {                   // align to int4 (2-edge) bound
    int2 e = edges[start];
    uint32_t u = m32[(size_t)e.x * 64 + lane];
    float nrm = __int_as_float(e.y);
    ax0 = fmaf(nrm, bfLo(u), ax0);
    ay0 = fmaf(nrm, bfHi(u), ay0);
    i = 1;
  }
  for (; i + 8 <= n; i += 8) {
    const int4* ep = (const int4*)(edges + start + i);   // 16B-aligned
    int4 q0 = ep[0], q1 = ep[1], q2 = ep[2], q3 = ep[3];
    uint32_t u0 = m32[(size_t)q0.x * 64 + lane];
    uint32_t u1 = m32[(size_t)q0.z * 64 + lane];
    uint32_t u2 = m32[(size_t)q1.x * 64 + lane];
    uint32_t u3 = m32[(size_t)q1.z * 64 + lane];
    uint32_t u4 = m32[(size_t)q2.x * 64 + lane];
    uint32_t u5 = m32[(size_t)q2.z * 64 + lane];
    uint32_t u6 = m32[(size_t)q3.x * 64 + lane];
    uint32_t u7 = m32[(size_t)q3.z * 64 + lane];
    float n0 = __int_as_float(q0.y), n1 = __int_as_float(q0.w);
    float n2 = __int_as_float(q1.y), n3 = __int_as_float(q1.w);
    float n4 = __int_as_float(q2.y), n5 = __int_as_float(q2.w);
    float n6 = __int_as_float(q3.y), n7 = __int_as_float(q3.w);
    ax0 = fmaf(n0, bfLo(u0), ax0); ay0 = fmaf(n0, bfHi(u0), ay0);
    ax1 = fmaf(n1, bfLo(u1), ax1); ay1 = fmaf(n1, bfHi(u1), ay1);
    ax2 = fmaf(n2, bfLo(u2), ax2); ay2 = fmaf(n2, bfHi(u2), ay2);
    ax3 = fmaf(n3, bfLo(u3), ax3); ay3 = fmaf(n3, bfHi(u3), ay3);
    ax0 = fmaf(n4, bfLo(u4), ax0); ay0 = fmaf(n4, bfHi(u4), ay0);
    ax1 = fmaf(n5, bfLo(u5), ax1); ay1 = fmaf(n5, bfHi(u5), ay1);
    ax2 = fmaf(n6, bfLo(u6), ax2); ay2 = fmaf(n6, bfHi(u6), ay2);
    ax3 = fmaf(n7, bfLo(u7), ax3); ay3 = fmaf(n7, bfHi(u7), ay3);
  }
  for (; i < n; ++i) {
    int2 e = edges[start + i];
    float nrm = __int_as_float(e.y);
    uint32_t u = m32[(size_t)e.x * 64 + lane];
    ax0 = fmaf(nrm, bfLo(u), ax0);
    ay0 = fmaf(nrm, bfHi(u), ay0);
  }
  float ax = (ax0 + ax1) + (ax2 + ax3);
  float ay = (ay0 + ay1) + (ay2 + ay3);
  if (MODE == 2) {
    ((float2*)outp)[(size_t)v * 64 + lane] = make_float2(ax * di, ay * di);
  } else {
    ax = fmaf(ax, di, bias[2 * lane]);
    ay = fmaf(ay, di, bias[2 * lane + 1]);
    ax = fmaxf(ax, 0.f);
    ay = fmaxf(ay, 0.f);
    ushort2 h2;
    h2.x = f2bf(ax);
    h2.y = f2bf(ay);
    ((ushort2*)outp)[(size_t)v * 64 + lane] = h2;
  }
}

// ---------------- pool: segment-sum a3 over batch-sorted nodes -----------
__global__ __launch_bounds__(256) void pool_sum(const float* __restrict__ a3,
                                                const int* __restrict__ batch,
                                                float* __restrict__ P) {
  int wave = blockIdx.x * 4 + (threadIdx.x >> 6);
  int lane = threadIdx.x & 63;
  int v0 = wave * 16;
  if (v0 >= N_NODES) return;
  int vend = v0 + 16;
  if (vend > N_NODES) vend = N_NODES;
  const float2* a2 = (const float2*)a3;
  float ax = 0.f, ay = 0.f;
  int g = batch[v0];
  for (int v = v0; v < vend; ++v) {
    int gv = batch[v];
    if (gv != g) {
      atomicAdd(&P[(size_t)g * FEAT + 2 * lane], ax);
      atomicAdd(&P[(size_t)g * FEAT + 2 * lane + 1], ay);
      ax = 0.f; ay = 0.f; g = gv;
    }
    float2 t = a2[(size_t)v * 64 + lane];
    ax += t.x;
    ay += t.y;
  }
  atomicAdd(&P[(size_t)g * FEAT + 2 * lane], ax);
  atomicAdd(&P[(size_t)g * FEAT + 2 * lane + 1], ay);
}

// ---------------- per-layer FC head --------------------------------------
// One kernel per layer; stream order is the inter-layer sync. Wave layout:
// lane <-> output col (coalesced 256B weight rows), 4 graphs per block
// (weight slice reused via L1). Split-K layers atomicAdd pre-activation
// (bias folded into part 0; OUT zero-initialized); consumers apply ReLU
// on read (RELU_IN). DIVC folds the mean-pool divide into the input read.
template <int K, int C, int KSLICE, int RELU_IN, int DIVC, int NSPLIT>
__global__ __launch_bounds__(256) void fc_layer(const float* __restrict__ IN,
                                                const float* __restrict__ W,
                                                const float* __restrict__ Bs,
                                                const float* __restrict__ cntg,
                                                float* __restrict__ OUT) {
  constexpr int CB = (C + 63) / 64;
  int lane = threadIdx.x & 63;
  int gq = threadIdx.x >> 6;
  int bid = blockIdx.x;
  int kp = bid % NSPLIT;
  int rest = bid / NSPLIT;
  int cg = rest % CB;
  int g = (rest / CB) * 4 + gq;
  int c = cg * 64 + lane;
  if (c >= C) return;
  int k0 = kp * KSLICE;
  const float* wp = W + (size_t)k0 * C + c;
  const float* in = IN + (size_t)g * K + k0;
  float cf = 1.f;
  if (DIVC) cf = fmaxf(cntg[g], 1.f);
  float a0 = 0.f, a1 = 0.f, a2 = 0.f, a3 = 0.f;
  float a4 = 0.f, a5 = 0.f, a6 = 0.f, a7 = 0.f;
#pragma unroll 2
  for (int k = 0; k < KSLICE; k += 8) {
    float i0 = in[k + 0], i1 = in[k + 1], i2 = in[k + 2], i3 = in[k + 3];
    float i4 = in[k + 4], i5 = in[k + 5], i6 = in[k + 6], i7 = in[k + 7];
    if (RELU_IN) {
      i0 = fmaxf(i0, 0.f); i1 = fmaxf(i1, 0.f);
      i2 = fmaxf(i2, 0.f); i3 = fmaxf(i3, 0.f);
      i4 = fmaxf(i4, 0.f); i5 = fmaxf(i5, 0.f);
      i6 = fmaxf(i6, 0.f); i7 = fmaxf(i7, 0.f);
    }
    if (DIVC) {
      i0 /= cf; i1 /= cf; i2 /= cf; i3 /= cf;
      i4 /= cf; i5 /= cf; i6 /= cf; i7 /= cf;
    }
    a0 = fmaf(i0, wp[(size_t)(k + 0) * C], a0);
    a1 = fmaf(i1, wp[(size_t)(k + 1) * C], a1);
    a2 = fmaf(i2, wp[(size_t)(k + 2) * C], a2);
    a3 = fmaf(i3, wp[(size_t)(k + 3) * C], a3);
    a4 = fmaf(i4, wp[(size_t)(k + 4) * C], a4);
    a5 = fmaf(i5, wp[(size_t)(k + 5) * C], a5);
    a6 = fmaf(i6, wp[(size_t)(k + 6) * C], a6);
    a7 = fmaf(i7, wp[(size_t)(k + 7) * C], a7);
  }
  float s = ((a0 + a1) + (a2 + a3)) + ((a4 + a5) + (a6 + a7));
  if (NSPLIT == 1) {
    OUT[(size_t)g * C + c] = s + Bs[c];
  } else {
    atomicAdd(&OUT[(size_t)g * C + c], s + (kp == 0 ? Bs[c] : 0.f));
  }
}

// =========================================================================
extern "C" void kernel_launch(void* const* d_in, const int* in_sizes, int n_in,
                              void* d_out, int out_size, void* d_ws, size_t ws_size,
                              hipStream_t stream) {
  const float* x         = (const float*)d_in[0];
  const int*   ei        = (const int*)d_in[1];     // [2][E]: row0 src, row1 dst
  const int*   batch     = (const int*)d_in[2];
  const float* conv_w[3] = {(const float*)d_in[3], (const float*)d_in[5], (const float*)d_in[7]};
  const float* conv_b[3] = {(const float*)d_in[4], (const float*)d_in[6], (const float*)d_in[8]};
  const float* fc_w[5]   = {(const float*)d_in[9],  (const float*)d_in[11],
                            (const float*)d_in[13], (const float*)d_in[15],
                            (const float*)d_in[17]};
  const float* fc_b[5]   = {(const float*)d_in[10], (const float*)d_in[12],
                            (const float*)d_in[14], (const float*)d_in[16],
                            (const float*)d_in[18]};
  const int* e_src = ei;
  const int* e_dst = ei + N_EDGES;
  float* out_f = (float*)d_out;                  // [64][128] fp32  (output 0)
  float* out_y = (float*)d_out + NGRAPH * FEAT;  // [64][10]  fp32  (output 1)

  char* p = (char*)d_ws;
  auto carve = [&](size_t bytes) {
    char* r = p;
    p += (bytes + 255) & ~(size_t)255;
    return r;
  };
  int*    cnt_i   = (int*)carve(N_NODES * 4);
  float*  dinv    = (float*)carve(N_NODES * 4);
  int*    csr_ptr = (int*)carve(N_NODES * 4);
  int*    bsums   = (int*)carve(256 * 4);
  int2*   edges   = (int2*)carve((size_t)N_EDGES * 8);            // {src, dinv_s}
  ushort* wbT     = (ushort*)carve((size_t)2 * FEAT * FEAT * 2);  // bf16 W^T conv1/2
  ushort* hbuf    = (ushort*)carve((size_t)N_NODES * FEAT * 2);   // bf16 h
  float*  f_sum   = (float*)carve(NGRAPH * FEAT * 4);             // P
  float*  cnt_g   = (float*)carve(NGRAPH * 4);                    // adjacent to f_sum
  float*  Y1      = (float*)carve(NGRAPH * 1024 * 4);             // fc1 pre-act
  float*  Y2      = (float*)carve(NGRAPH * 512 * 4);              // fc2 pre-act (atomic)
  float*  Y3      = (float*)carve(NGRAPH * 256 * 4);              // fc3 pre-act (atomic)
  float*  Y4      = (float*)carve(NGRAPH * 128 * 4);              // fc4 pre-act (atomic)
  // Shared region (25.6 MB): rank (3.2M) + msl (12.8M) live early; a3 (fp32
  // [N][128]) overlays the whole region. rank dead after fill_csr; msl dead
  // after each agg<0> reads it; a3 written by agg<2> which reads only
  // hbuf/edges/ptr/cnt -> no overlap hazard.
  char*   region  = carve((size_t)N_NODES * FEAT * 4);
  int*    rank    = (int*)region;
  ushort* msl     = (ushort*)(region + (size_t)N_EDGES * 4);
  float*  a3      = (float*)region;

  const int BLK_N = (N_NODES + 255) / 256;   // 196

  // zero-init (ws + out are poisoned 0xAA each timed call)
  hipMemsetAsync(cnt_i, 0, N_NODES * 4, stream);
  hipMemsetAsync(f_sum, 0, NGRAPH * FEAT * 4 + 256, stream);      // f_sum + cnt_g
  hipMemsetAsync(Y2, 0, NGRAPH * (512 + 256 + 128) * 4, stream);  // atomic targets

  // ---- tiny weight transpose-cvt (feeds gemm_rank) ----
  wcvt<<<32, 256, 0, stream>>>(conv_w[0], conv_w[1], wbT);

  // ---- K1: conv1 gemm (fp32 A, in-reg cvt) overlapped with rank atomics --
  gemm_rank<<<GR_BLKS, 256, 0, stream>>>(x, wbT, msl, e_dst, cnt_i, rank);

  // ---- dinv + graph counts + scan1 (1 dispatch) ----
  dinv_scan1<<<BLK_N, 256, 0, stream>>>(cnt_i, batch, dinv, cnt_g, csr_ptr, bsums);
  scan2<<<1, 256, 0, stream>>>(bsums, BLK_N);
  scan3<<<BLK_N, 256, 0, stream>>>(csr_ptr, bsums);

  // ---- atomic-free CSR fill ----
  fill_csr<<<E_BLKS, 256, 0, stream>>>(e_src, e_dst, rank, csr_ptr, dinv, edges);

  const int AGG_BLKS  = (N_NODES + 3) / 4;
  const int POOL_BLKS = (N_NODES / 16 + 3) / 4 + 1;

  // ---- conv1 agg: h1 = relu(di*acc + b1) ----
  agg_kernel<0><<<AGG_BLKS, 256, 0, stream>>>(msl, dinv, csr_ptr, cnt_i, edges,
                                              conv_b[0], hbuf);
  // ---- conv2: msg2 = h1 W2; h2 = relu(di*acc + b2) ----
  gemm128<<<GEMM_BLKS, 256, 0, stream>>>(hbuf, wbT + FEAT * FEAT, msl);
  agg_kernel<0><<<AGG_BLKS, 256, 0, stream>>>(msl, dinv, csr_ptr, cnt_i, edges,
                                              conv_b[1], hbuf);
  // ---- conv3 pre-pool: a3 = di*acc(h2), fp32 ----
  agg_kernel<2><<<AGG_BLKS, 256, 0, stream>>>(hbuf, dinv, csr_ptr, cnt_i, edges,
                                              nullptr, a3);
  // ---- per-graph segment sum (batch sorted) ----
  pool_sum<<<POOL_BLKS, 256, 0, stream>>>(a3, batch, f_sum);

  // ---- per-layer head: Pn@W3 -> fc1..fc5 (stream-ordered) ----
  //          K     C   KSL  RELU DIV SPLIT        grid = (C/64)*16*SPLIT
  fc_layer< 128, 128, 128, 0, 1, 1><<< 32, 256, 0, stream>>>(f_sum, conv_w[2], conv_b[2], cnt_g, out_f);
  fc_layer< 128,1024, 128, 0, 0, 1><<<256, 256, 0, stream>>>(out_f, fc_w[0], fc_b[0], nullptr, Y1);
  fc_layer<1024, 512, 256, 1, 0, 4><<<512, 256, 0, stream>>>(Y1, fc_w[1], fc_b[1], nullptr, Y2);
  fc_layer< 512, 256, 128, 1, 0, 4><<<256, 256, 0, stream>>>(Y2, fc_w[2], fc_b[2], nullptr, Y3);
  fc_layer< 256, 128,  32, 1, 0, 8><<<256, 256, 0, stream>>>(Y3, fc_w[3], fc_b[3], nullptr, Y4);
  fc_layer< 128,  10, 128, 1, 0, 1><<< 16, 256, 0, stream>>>(Y4, fc_w[4], fc_b[4], nullptr, out_y);
}

// Round 6
// 374.022 us; speedup vs baseline: 1.0374x; 1.0027x over previous
//
#include <hip/hip_runtime.h>
#include <stdint.h>

#define N_NODES 50000
#define N_EDGES 800000
#define FEAT    128
#define NGRAPH  64

#define E_BLKS      3125   // 800000 edges / 256
#define GSTRIP_BLKS 782    // ceil(3125 row-strips / 4 waves)
#define GR_BLKS     (GSTRIP_BLKS + E_BLKS)   // 3907, interleaved 1:4

typedef __attribute__((ext_vector_type(8))) short short8;
typedef __attribute__((ext_vector_type(4))) float floatx4;

static __device__ __forceinline__ ushort f2bf(float f) {
  uint32_t x = __float_as_uint(f);
  x += 0x7FFF + ((x >> 16) & 1);   // RNE
  return (ushort)(x >> 16);
}
static __device__ __forceinline__ float bfLo(uint32_t u) {
  return __uint_as_float(u << 16);
}
static __device__ __forceinline__ float bfHi(uint32_t u) {
  return __uint_as_float(u & 0xFFFF0000u);
}

// cvt + transpose: in is row-major [128][128] fp32 [k][n], out is [n][k] bf16
static __device__ __forceinline__ void cvt4T(const float* __restrict__ in,
                                             ushort* __restrict__ outT, int i) {
  float4 v = ((const float4*)in)[i];
  int k = (4 * i) >> 7;          // row
  int n = (4 * i) & 127;         // col
  outT[(size_t)(n + 0) * FEAT + k] = f2bf(v.x);
  outT[(size_t)(n + 1) * FEAT + k] = f2bf(v.y);
  outT[(size_t)(n + 2) * FEAT + k] = f2bf(v.z);
  outT[(size_t)(n + 3) * FEAT + k] = f2bf(v.w);
}

// ---- tiny: transpose-cvt both conv weights (runs before gemm_rank) ------
__global__ __launch_bounds__(256) void wcvt(const float* __restrict__ w0,
                                            const float* __restrict__ w1,
                                            ushort* __restrict__ wbT) {
  int i = blockIdx.x * 256 + threadIdx.x;   // 0..8191
  if (i < 4096) cvt4T(w0, wbT, i);
  else cvt4T(w1, wbT + FEAT * FEAT, i - 4096);
}

// ---- row-strip gemm: wave owns a 16x128 output strip --------------------
// A (fp32, in-reg bf16 cvt) loaded ONCE into 4 short8 regs, reused across
// all 8 n-tiles (vs 8x reload in the old 1-tile/wave layout). 32 MFMA/wave.
static __device__ __forceinline__ void gemm_strip_f32a(int strip, int lane,
                                                       const float* __restrict__ X,
                                                       const ushort* __restrict__ WT,
                                                       ushort* __restrict__ XW) {
  if (strip >= N_NODES / 16) return;
  int m0 = strip * 16;
  int r = lane & 15, quad = lane >> 4;
  const float* xrow = X + (size_t)(m0 + r) * FEAT;
  short8 afr[4];
#pragma unroll
  for (int kb = 0; kb < 4; ++kb) {
    int k0 = kb * 32 + quad * 8;
    float4 f0 = *(const float4*)(xrow + k0);
    float4 f1 = *(const float4*)(xrow + k0 + 4);
    short8 a;
    a[0] = (short)f2bf(f0.x); a[1] = (short)f2bf(f0.y);
    a[2] = (short)f2bf(f0.z); a[3] = (short)f2bf(f0.w);
    a[4] = (short)f2bf(f1.x); a[5] = (short)f2bf(f1.y);
    a[6] = (short)f2bf(f1.z); a[7] = (short)f2bf(f1.w);
    afr[kb] = a;
  }
#pragma unroll
  for (int nt = 0; nt < 8; ++nt) {
    int n0 = nt * 16;
    floatx4 acc = {0.f, 0.f, 0.f, 0.f};
    const ushort* wrow = WT + (size_t)(n0 + r) * FEAT;
#pragma unroll
    for (int kb = 0; kb < 4; ++kb) {
      short8 b = *(const short8*)(wrow + kb * 32 + quad * 8);
      acc = __builtin_amdgcn_mfma_f32_16x16x32_bf16(afr[kb], b, acc, 0, 0, 0);
    }
#pragma unroll
    for (int reg = 0; reg < 4; ++reg)
      XW[(size_t)(m0 + quad * 4 + reg) * FEAT + n0 + r] = f2bf(acc[reg]);
  }
}

// ---- K1: conv1 gemm (row-strip) interleaved 1:4 with rank atomics -------
__global__ __launch_bounds__(256) void gemm_rank(const float* __restrict__ x,
                                                 const ushort* __restrict__ wbT,
                                                 ushort* __restrict__ msl,
                                                 const int* __restrict__ dst,
                                                 int* __restrict__ cnt,
                                                 int* __restrict__ rank) {
  int b = blockIdx.x, t = threadIdx.x;
  int fifth = b / 5;
  if (b - fifth * 5 == 0) {
    gemm_strip_f32a(fifth * 4 + (t >> 6), t & 63, x, wbT, msl);
  } else {
    int e = (b - fifth - 1) * 256 + t;         // 0..799999 exactly
    rank[e] = atomicAdd(&cnt[dst[e]], 1);
  }
}

// ---- fused: dinv + graph counts + scan1 (all read cnt) ------------------
__global__ __launch_bounds__(256) void dinv_scan1(const int* __restrict__ cnt,
                                                  const int* __restrict__ batch,
                                                  float* __restrict__ dinv,
                                                  float* __restrict__ cnt_g,
                                                  int* __restrict__ ptr,
                                                  int* __restrict__ bsums) {
  __shared__ int tmp[256];
  __shared__ int bins[NGRAPH];
  if (threadIdx.x < NGRAPH) bins[threadIdx.x] = 0;
  int i = blockIdx.x * 256 + threadIdx.x;
  int v = (i < N_NODES) ? cnt[i] : 0;
  tmp[threadIdx.x] = v;
  __syncthreads();
  for (int off = 1; off < 256; off <<= 1) {
    int t = (threadIdx.x >= off) ? tmp[threadIdx.x - off] : 0;
    __syncthreads();
    tmp[threadIdx.x] += t;
    __syncthreads();
  }
  if (i < N_NODES) ptr[i] = tmp[threadIdx.x] - v;           // exclusive
  if (threadIdx.x == 255) bsums[blockIdx.x] = tmp[255];
  if (i < N_NODES) {
    dinv[i] = rsqrtf((float)v + 1.0f);
    atomicAdd(&bins[batch[i]], 1);
  }
  __syncthreads();
  if (threadIdx.x < NGRAPH && bins[threadIdx.x] > 0)
    atomicAdd(&cnt_g[threadIdx.x], (float)bins[threadIdx.x]);
}

__global__ __launch_bounds__(256) void scan2(int* __restrict__ bsums, int nb) {
  __shared__ int tmp[256];
  int v = (threadIdx.x < nb) ? bsums[threadIdx.x] : 0;
  tmp[threadIdx.x] = v;
  __syncthreads();
  for (int off = 1; off < 256; off <<= 1) {
    int t = (threadIdx.x >= off) ? tmp[threadIdx.x - off] : 0;
    __syncthreads();
    tmp[threadIdx.x] += t;
    __syncthreads();
  }
  if (threadIdx.x < nb) bsums[threadIdx.x] = tmp[threadIdx.x] - v;  // exclusive
}

__global__ __launch_bounds__(256) void scan3(int* __restrict__ ptr,
                                             const int* __restrict__ bsums) {
  int i = blockIdx.x * 256 + threadIdx.x;
  if (i < N_NODES) ptr[i] += bsums[blockIdx.x];
}

// ---- fill: atomic-free CSR scatter, payload {src, dinv[src]} ------------
__global__ __launch_bounds__(256) void fill_csr(const int* __restrict__ src,
                                                const int* __restrict__ dst,
                                                const int* __restrict__ rank,
                                                const int* __restrict__ ptr,
                                                const float* __restrict__ dinv,
                                                int2* __restrict__ edges) {
  int e = blockIdx.x * 256 + threadIdx.x;
  if (e >= N_EDGES) return;
  int s = src[e];
  edges[ptr[dst[e]] + rank[e]] = make_int2(s, __float_as_int(dinv[s]));
}

// ---- edge-gather accumulator (8-edge ILP), shared by all agg kernels ----
static __device__ __forceinline__ float2 agg_node(const uint32_t* __restrict__ m32,
                                                  const int2* __restrict__ edges,
                                                  int start, int n, int lane) {
  float ax0 = 0.f, ay0 = 0.f, ax1 = 0.f, ay1 = 0.f;
  float ax2 = 0.f, ay2 = 0.f, ax3 = 0.f, ay3 = 0.f;
  int i = 0;
  if ((start & 1) && n > 0) {                   // align to int4 (2-edge) bound
    int2 e = edges[start];
    uint32_t u = m32[(size_t)e.x * 64 + lane];
    float nrm = __int_as_float(e.y);
    ax0 = fmaf(nrm, bfLo(u), ax0);
    ay0 = fmaf(nrm, bfHi(u), ay0);
    i = 1;
  }
  for (; i + 8 <= n; i += 8) {
    const int4* ep = (const int4*)(edges + start + i);   // 16B-aligned
    int4 q0 = ep[0], q1 = ep[1], q2 = ep[2], q3 = ep[3];
    uint32_t u0 = m32[(size_t)q0.x * 64 + lane];
    uint32_t u1 = m32[(size_t)q0.z * 64 + lane];
    uint32_t u2 = m32[(size_t)q1.x * 64 + lane];
    uint32_t u3 = m32[(size_t)q1.z * 64 + lane];
    uint32_t u4 = m32[(size_t)q2.x * 64 + lane];
    uint32_t u5 = m32[(size_t)q2.z * 64 + lane];
    uint32_t u6 = m32[(size_t)q3.x * 64 + lane];
    uint32_t u7 = m32[(size_t)q3.z * 64 + lane];
    float n0 = __int_as_float(q0.y), n1 = __int_as_float(q0.w);
    float n2 = __int_as_float(q1.y), n3 = __int_as_float(q1.w);
    float n4 = __int_as_float(q2.y), n5 = __int_as_float(q2.w);
    float n6 = __int_as_float(q3.y), n7 = __int_as_float(q3.w);
    ax0 = fmaf(n0, bfLo(u0), ax0); ay0 = fmaf(n0, bfHi(u0), ay0);
    ax1 = fmaf(n1, bfLo(u1), ax1); ay1 = fmaf(n1, bfHi(u1), ay1);
    ax2 = fmaf(n2, bfLo(u2), ax2); ay2 = fmaf(n2, bfHi(u2), ay2);
    ax3 = fmaf(n3, bfLo(u3), ax3); ay3 = fmaf(n3, bfHi(u3), ay3);
    ax0 = fmaf(n4, bfLo(u4), ax0); ay0 = fmaf(n4, bfHi(u4), ay0);
    ax1 = fmaf(n5, bfLo(u5), ax1); ay1 = fmaf(n5, bfHi(u5), ay1);
    ax2 = fmaf(n6, bfLo(u6), ax2); ay2 = fmaf(n6, bfHi(u6), ay2);
    ax3 = fmaf(n7, bfLo(u7), ax3); ay3 = fmaf(n7, bfHi(u7), ay3);
  }
  for (; i < n; ++i) {
    int2 e = edges[start + i];
    float nrm = __int_as_float(e.y);
    uint32_t u = m32[(size_t)e.x * 64 + lane];
    ax0 = fmaf(nrm, bfLo(u), ax0);
    ay0 = fmaf(nrm, bfHi(u), ay0);
  }
  return make_float2((ax0 + ax1) + (ax2 + ax3), (ay0 + ay1) + (ay2 + ay3));
}

// ---- fused conv1-agg + conv2-gemm: h1 never touches HBM -----------------
// Block = 16 nodes, 8 waves x 2 nodes. Each wave aggregates its 2 nodes'
// h1 rows (relu(di*acc+b1)), stages bf16 rows to LDS (+8 ushort pad kills
// the 256B-stride bank conflict), barrier, then each wave computes one
// 16x16 n-tile of msg2 = h1 @ W2 via 4 MFMA.
__global__ __launch_bounds__(512) void agg1_gemm2(const ushort* __restrict__ msg,
                                                  const float* __restrict__ dinv,
                                                  const int* __restrict__ ptr,
                                                  const int* __restrict__ cnt,
                                                  const int2* __restrict__ edges,
                                                  const float* __restrict__ bias,
                                                  const ushort* __restrict__ wT2,
                                                  ushort* __restrict__ msl2) {
  __shared__ ushort h1s[16][136];
  int w = threadIdx.x >> 6, lane = threadIdx.x & 63;
  int base = blockIdx.x * 16;
  const uint32_t* m32 = (const uint32_t*)msg;
  float blo = bias[2 * lane], bhi = bias[2 * lane + 1];
#pragma unroll
  for (int vi = 0; vi < 2; ++vi) {
    int li = w * 2 + vi;
    int v = base + li;
    float di = dinv[v];
    uint32_t su = m32[(size_t)v * 64 + lane];
    float2 s = agg_node(m32, edges, ptr[v], cnt[v], lane);
    float ax = fmaf(fmaf(di, bfLo(su), s.x), di, blo);
    float ay = fmaf(fmaf(di, bfHi(su), s.y), di, bhi);
    ushort2 hp;
    hp.x = f2bf(fmaxf(ax, 0.f));
    hp.y = f2bf(fmaxf(ay, 0.f));
    *(ushort2*)&h1s[li][2 * lane] = hp;
  }
  __syncthreads();
  int r = lane & 15, quad = lane >> 4;
  int n0 = w * 16;
  floatx4 acc = {0.f, 0.f, 0.f, 0.f};
  const ushort* wrow = wT2 + (size_t)(n0 + r) * FEAT;
#pragma unroll
  for (int kb = 0; kb < 4; ++kb) {
    int k0 = kb * 32 + quad * 8;
    short8 a = *(const short8*)&h1s[r][k0];
    short8 b = *(const short8*)(wrow + k0);
    acc = __builtin_amdgcn_mfma_f32_16x16x32_bf16(a, b, acc, 0, 0, 0);
  }
#pragma unroll
  for (int reg = 0; reg < 4; ++reg)
    msl2[(size_t)(base + quad * 4 + reg) * FEAT + n0 + r] = f2bf(acc[reg]);
}

// ---------------- aggregation (1 wave/node), conv2 + conv3 ---------------
// MODE 0: out bf16 = relu(di*acc + b)   (conv2 -> h2)
// MODE 2: out fp32 = di*acc             (conv3 pre-pool, no bias)
template <int MODE>
__global__ __launch_bounds__(256) void agg_kernel(const ushort* __restrict__ msg,
                                                  const float* __restrict__ dinv,
                                                  const int* __restrict__ ptr,
                                                  const int* __restrict__ cnt,
                                                  const int2* __restrict__ edges,
                                                  const float* __restrict__ bias,
                                                  void* __restrict__ outp) {
  int wave = (blockIdx.x * 256 + threadIdx.x) >> 6;
  int lane = threadIdx.x & 63;
  if (wave >= N_NODES) return;
  int v = wave;
  float di = dinv[v];
  const uint32_t* m32 = (const uint32_t*)msg;   // 64 dwords per node row
  uint32_t su = m32[(size_t)v * 64 + lane];     // self term, weight di
  float2 s = agg_node(m32, edges, ptr[v], cnt[v], lane);
  float ax = fmaf(di, bfLo(su), s.x);
  float ay = fmaf(di, bfHi(su), s.y);
  if (MODE == 2) {
    ((float2*)outp)[(size_t)v * 64 + lane] = make_float2(ax * di, ay * di);
  } else {
    ax = fmaf(ax, di, bias[2 * lane]);
    ay = fmaf(ay, di, bias[2 * lane + 1]);
    ushort2 h2;
    h2.x = f2bf(fmaxf(ax, 0.f));
    h2.y = f2bf(fmaxf(ay, 0.f));
    ((ushort2*)outp)[(size_t)v * 64 + lane] = h2;
  }
}

// ---------------- pool: segment-sum a3 over batch-sorted nodes -----------
__global__ __launch_bounds__(256) void pool_sum(const float* __restrict__ a3,
                                                const int* __restrict__ batch,
                                                float* __restrict__ P) {
  int wave = blockIdx.x * 4 + (threadIdx.x >> 6);
  int lane = threadIdx.x & 63;
  int v0 = wave * 16;
  if (v0 >= N_NODES) return;
  int vend = v0 + 16;
  if (vend > N_NODES) vend = N_NODES;
  const float2* a2 = (const float2*)a3;
  float ax = 0.f, ay = 0.f;
  int g = batch[v0];
  for (int v = v0; v < vend; ++v) {
    int gv = batch[v];
    if (gv != g) {
      atomicAdd(&P[(size_t)g * FEAT + 2 * lane], ax);
      atomicAdd(&P[(size_t)g * FEAT + 2 * lane + 1], ay);
      ax = 0.f; ay = 0.f; g = gv;
    }
    float2 t = a2[(size_t)v * 64 + lane];
    ax += t.x;
    ay += t.y;
  }
  atomicAdd(&P[(size_t)g * FEAT + 2 * lane], ax);
  atomicAdd(&P[(size_t)g * FEAT + 2 * lane + 1], ay);
}

// ---------------- per-layer FC head --------------------------------------
template <int K, int C, int KSLICE, int RELU_IN, int DIVC, int NSPLIT>
__global__ __launch_bounds__(256) void fc_layer(const float* __restrict__ IN,
                                                const float* __restrict__ W,
                                                const float* __restrict__ Bs,
                                                const float* __restrict__ cntg,
                                                float* __restrict__ OUT) {
  constexpr int CB = (C + 63) / 64;
  int lane = threadIdx.x & 63;
  int gq = threadIdx.x >> 6;
  int bid = blockIdx.x;
  int kp = bid % NSPLIT;
  int rest = bid / NSPLIT;
  int cg = rest % CB;
  int g = (rest / CB) * 4 + gq;
  int c = cg * 64 + lane;
  if (c >= C) return;
  int k0 = kp * KSLICE;
  const float* wp = W + (size_t)k0 * C + c;
  const float* in = IN + (size_t)g * K + k0;
  float cf = 1.f;
  if (DIVC) cf = fmaxf(cntg[g], 1.f);
  float a0 = 0.f, a1 = 0.f, a2 = 0.f, a3 = 0.f;
  float a4 = 0.f, a5 = 0.f, a6 = 0.f, a7 = 0.f;
#pragma unroll 2
  for (int k = 0; k < KSLICE; k += 8) {
    float i0 = in[k + 0], i1 = in[k + 1], i2 = in[k + 2], i3 = in[k + 3];
    float i4 = in[k + 4], i5 = in[k + 5], i6 = in[k + 6], i7 = in[k + 7];
    if (RELU_IN) {
      i0 = fmaxf(i0, 0.f); i1 = fmaxf(i1, 0.f);
      i2 = fmaxf(i2, 0.f); i3 = fmaxf(i3, 0.f);
      i4 = fmaxf(i4, 0.f); i5 = fmaxf(i5, 0.f);
      i6 = fmaxf(i6, 0.f); i7 = fmaxf(i7, 0.f);
    }
    if (DIVC) {
      i0 /= cf; i1 /= cf; i2 /= cf; i3 /= cf;
      i4 /= cf; i5 /= cf; i6 /= cf; i7 /= cf;
    }
    a0 = fmaf(i0, wp[(size_t)(k + 0) * C], a0);
    a1 = fmaf(i1, wp[(size_t)(k + 1) * C], a1);
    a2 = fmaf(i2, wp[(size_t)(k + 2) * C], a2);
    a3 = fmaf(i3, wp[(size_t)(k + 3) * C], a3);
    a4 = fmaf(i4, wp[(size_t)(k + 4) * C], a4);
    a5 = fmaf(i5, wp[(size_t)(k + 5) * C], a5);
    a6 = fmaf(i6, wp[(size_t)(k + 6) * C], a6);
    a7 = fmaf(i7, wp[(size_t)(k + 7) * C], a7);
  }
  float s = ((a0 + a1) + (a2 + a3)) + ((a4 + a5) + (a6 + a7));
  if (NSPLIT == 1) {
    OUT[(size_t)g * C + c] = s + Bs[c];
  } else {
    atomicAdd(&OUT[(size_t)g * C + c], s + (kp == 0 ? Bs[c] : 0.f));
  }
}

// =========================================================================
extern "C" void kernel_launch(void* const* d_in, const int* in_sizes, int n_in,
                              void* d_out, int out_size, void* d_ws, size_t ws_size,
                              hipStream_t stream) {
  const float* x         = (const float*)d_in[0];
  const int*   ei        = (const int*)d_in[1];     // [2][E]: row0 src, row1 dst
  const int*   batch     = (const int*)d_in[2];
  const float* conv_w[3] = {(const float*)d_in[3], (const float*)d_in[5], (const float*)d_in[7]};
  const float* conv_b[3] = {(const float*)d_in[4], (const float*)d_in[6], (const float*)d_in[8]};
  const float* fc_w[5]   = {(const float*)d_in[9],  (const float*)d_in[11],
                            (const float*)d_in[13], (const float*)d_in[15],
                            (const float*)d_in[17]};
  const float* fc_b[5]   = {(const float*)d_in[10], (const float*)d_in[12],
                            (const float*)d_in[14], (const float*)d_in[16],
                            (const float*)d_in[18]};
  const int* e_src = ei;
  const int* e_dst = ei + N_EDGES;
  float* out_f = (float*)d_out;                  // [64][128] fp32  (output 0)
  float* out_y = (float*)d_out + NGRAPH * FEAT;  // [64][10]  fp32  (output 1)

  char* p = (char*)d_ws;
  auto carve = [&](size_t bytes) {
    char* r = p;
    p += (bytes + 255) & ~(size_t)255;
    return r;
  };
  int*    cnt_i   = (int*)carve(N_NODES * 4);
  float*  dinv    = (float*)carve(N_NODES * 4);
  int*    csr_ptr = (int*)carve(N_NODES * 4);
  int*    bsums   = (int*)carve(256 * 4);
  int2*   edges   = (int2*)carve((size_t)N_EDGES * 8);            // {src, dinv_s}
  ushort* wbT     = (ushort*)carve((size_t)2 * FEAT * FEAT * 2);  // bf16 W^T conv1/2
  ushort* h2buf   = (ushort*)carve((size_t)N_NODES * FEAT * 2);   // bf16 h2
  float*  f_sum   = (float*)carve(NGRAPH * FEAT * 4);             // P
  float*  cnt_g   = (float*)carve(NGRAPH * 4);                    // adjacent to f_sum
  float*  Y1      = (float*)carve(NGRAPH * 1024 * 4);             // fc1 pre-act
  float*  Y2      = (float*)carve(NGRAPH * 512 * 4);              // fc2 pre-act (atomic)
  float*  Y3      = (float*)carve(NGRAPH * 256 * 4);              // fc3 pre-act (atomic)
  float*  Y4      = (float*)carve(NGRAPH * 128 * 4);              // fc4 pre-act (atomic)
  // Shared region (28.8 MB): [rank 3.2M][msl1 12.8M][msl2 12.8M].
  // Lifetimes: rank [gemm_rank..fill_csr]; msl1 [gemm_rank..agg1_gemm2];
  // msl2 [agg1_gemm2..agg<0>]. a3 (25.6M fp32) overlays the region start,
  // written by agg<2> when rank/msl1/msl2 are all dead. No overlap hazard.
  char*   region  = carve((size_t)N_EDGES * 4 + 2 * (size_t)N_NODES * FEAT * 2);
  int*    rank    = (int*)region;
  ushort* msl1    = (ushort*)(region + (size_t)N_EDGES * 4);
  ushort* msl2    = (ushort*)(region + (size_t)N_EDGES * 4 + (size_t)N_NODES * FEAT * 2);
  float*  a3      = (float*)region;

  const int BLK_N = (N_NODES + 255) / 256;   // 196

  // zero-init (ws + out are poisoned 0xAA each timed call)
  hipMemsetAsync(cnt_i, 0, N_NODES * 4, stream);
  hipMemsetAsync(f_sum, 0, NGRAPH * FEAT * 4 + 256, stream);      // f_sum + cnt_g
  hipMemsetAsync(Y2, 0, NGRAPH * (512 + 256 + 128) * 4, stream);  // atomic targets

  // ---- tiny weight transpose-cvt (feeds gemm_rank) ----
  wcvt<<<32, 256, 0, stream>>>(conv_w[0], conv_w[1], wbT);

  // ---- K1: conv1 row-strip gemm overlapped with rank atomics ----
  gemm_rank<<<GR_BLKS, 256, 0, stream>>>(x, wbT, msl1, e_dst, cnt_i, rank);

  // ---- dinv + graph counts + scan1 (1 dispatch) ----
  dinv_scan1<<<BLK_N, 256, 0, stream>>>(cnt_i, batch, dinv, cnt_g, csr_ptr, bsums);
  scan2<<<1, 256, 0, stream>>>(bsums, BLK_N);
  scan3<<<BLK_N, 256, 0, stream>>>(csr_ptr, bsums);

  // ---- atomic-free CSR fill ----
  fill_csr<<<E_BLKS, 256, 0, stream>>>(e_src, e_dst, rank, csr_ptr, dinv, edges);

  const int AGG_BLKS  = (N_NODES + 3) / 4;
  const int POOL_BLKS = (N_NODES / 16 + 3) / 4 + 1;

  // ---- conv1 agg + conv2 gemm fused: msl2 = relu-agg(msl1) @ W2 ----
  agg1_gemm2<<<N_NODES / 16, 512, 0, stream>>>(msl1, dinv, csr_ptr, cnt_i, edges,
                                               conv_b[0], wbT + FEAT * FEAT, msl2);
  // ---- conv2 agg: h2 = relu(di*acc + b2) ----
  agg_kernel<0><<<AGG_BLKS, 256, 0, stream>>>(msl2, dinv, csr_ptr, cnt_i, edges,
                                              conv_b[1], h2buf);
  // ---- conv3 pre-pool: a3 = di*acc(h2), fp32 ----
  agg_kernel<2><<<AGG_BLKS, 256, 0, stream>>>(h2buf, dinv, csr_ptr, cnt_i, edges,
                                              nullptr, a3);
  // ---- per-graph segment sum (batch sorted) ----
  pool_sum<<<POOL_BLKS, 256, 0, stream>>>(a3, batch, f_sum);

  // ---- per-layer head: Pn@W3 -> fc1..fc5 (stream-ordered) ----
  fc_layer< 128, 128, 128, 0, 1, 1><<< 32, 256, 0, stream>>>(f_sum, conv_w[2], conv_b[2], cnt_g, out_f);
  fc_layer< 128,1024, 128, 0, 0, 1><<<256, 256, 0, stream>>>(out_f, fc_w[0], fc_b[0], nullptr, Y1);
  fc_layer<1024, 512, 256, 1, 0, 4><<<512, 256, 0, stream>>>(Y1, fc_w[1], fc_b[1], nullptr, Y2);
  fc_layer< 512, 256, 128, 1, 0, 4><<<256, 256, 0, stream>>>(Y2, fc_w[2], fc_b[2], nullptr, Y3);
  fc_layer< 256, 128,  32, 1, 0, 8><<<256, 256, 0, stream>>>(Y3, fc_w[3], fc_b[3], nullptr, Y4);
  fc_layer< 128,  10, 128, 1, 0, 1><<< 16, 256, 0, stream>>>(Y4, fc_w[4], fc_b[4], nullptr, out_y);
}

// Round 7
// 369.464 us; speedup vs baseline: 1.0502x; 1.0123x over previous
//
#include <hip/hip_runtime.h>
#include <stdint.h>

#define N_NODES 50000
#define N_EDGES 800000
#define FEAT    128
#define NGRAPH  64

#define E_BLKS      3125   // 800000 edges / 256
#define GSTRIP_BLKS 782    // ceil(3125 row-strips / 4 waves)
#define GR_BLKS     (GSTRIP_BLKS + E_BLKS)   // interleaved 1:4

typedef __attribute__((ext_vector_type(8))) short short8;
typedef __attribute__((ext_vector_type(4))) float floatx4;

static __device__ __forceinline__ ushort f2bf(float f) {
  uint32_t x = __float_as_uint(f);
  x += 0x7FFF + ((x >> 16) & 1);   // RNE
  return (ushort)(x >> 16);
}
static __device__ __forceinline__ float bfLo(uint32_t u) {
  return __uint_as_float(u << 16);
}
static __device__ __forceinline__ float bfHi(uint32_t u) {
  return __uint_as_float(u & 0xFFFF0000u);
}

// cvt + transpose: in is row-major [128][128] fp32 [k][n], out is [n][k] bf16
static __device__ __forceinline__ void cvt4T(const float* __restrict__ in,
                                             ushort* __restrict__ outT, int i) {
  float4 v = ((const float4*)in)[i];
  int k = (4 * i) >> 7;          // row
  int n = (4 * i) & 127;         // col
  outT[(size_t)(n + 0) * FEAT + k] = f2bf(v.x);
  outT[(size_t)(n + 1) * FEAT + k] = f2bf(v.y);
  outT[(size_t)(n + 2) * FEAT + k] = f2bf(v.z);
  outT[(size_t)(n + 3) * FEAT + k] = f2bf(v.w);
}

// ---- tiny: transpose-cvt both conv weights (runs before gemm_rank) ------
__global__ __launch_bounds__(256) void wcvt(const float* __restrict__ w0,
                                            const float* __restrict__ w1,
                                            ushort* __restrict__ wbT) {
  int i = blockIdx.x * 256 + threadIdx.x;   // 0..8191
  if (i < 4096) cvt4T(w0, wbT, i);
  else cvt4T(w1, wbT + FEAT * FEAT, i - 4096);
}

// ---- row-strip gemm, A from fp32 (in-reg cvt): wave owns 16x128 strip ---
static __device__ __forceinline__ void gemm_strip_f32a(int strip, int lane,
                                                       const float* __restrict__ X,
                                                       const ushort* __restrict__ WT,
                                                       ushort* __restrict__ XW) {
  if (strip >= N_NODES / 16) return;
  int m0 = strip * 16;
  int r = lane & 15, quad = lane >> 4;
  const float* xrow = X + (size_t)(m0 + r) * FEAT;
  short8 afr[4];
#pragma unroll
  for (int kb = 0; kb < 4; ++kb) {
    int k0 = kb * 32 + quad * 8;
    float4 f0 = *(const float4*)(xrow + k0);
    float4 f1 = *(const float4*)(xrow + k0 + 4);
    short8 a;
    a[0] = (short)f2bf(f0.x); a[1] = (short)f2bf(f0.y);
    a[2] = (short)f2bf(f0.z); a[3] = (short)f2bf(f0.w);
    a[4] = (short)f2bf(f1.x); a[5] = (short)f2bf(f1.y);
    a[6] = (short)f2bf(f1.z); a[7] = (short)f2bf(f1.w);
    afr[kb] = a;
  }
#pragma unroll
  for (int nt = 0; nt < 8; ++nt) {
    int n0 = nt * 16;
    floatx4 acc = {0.f, 0.f, 0.f, 0.f};
    const ushort* wrow = WT + (size_t)(n0 + r) * FEAT;
#pragma unroll
    for (int kb = 0; kb < 4; ++kb) {
      short8 b = *(const short8*)(wrow + kb * 32 + quad * 8);
      acc = __builtin_amdgcn_mfma_f32_16x16x32_bf16(afr[kb], b, acc, 0, 0, 0);
    }
#pragma unroll
    for (int reg = 0; reg < 4; ++reg)
      XW[(size_t)(m0 + quad * 4 + reg) * FEAT + n0 + r] = f2bf(acc[reg]);
  }
}

// ---- K1: conv1 gemm (row-strip) interleaved 1:4 with rank atomics -------
__global__ __launch_bounds__(256) void gemm_rank(const float* __restrict__ x,
                                                 const ushort* __restrict__ wbT,
                                                 ushort* __restrict__ msl,
                                                 const int* __restrict__ dst,
                                                 int* __restrict__ cnt,
                                                 int* __restrict__ rank) {
  int b = blockIdx.x, t = threadIdx.x;
  int fifth = b / 5;
  if (b - fifth * 5 == 0) {
    gemm_strip_f32a(fifth * 4 + (t >> 6), t & 63, x, wbT, msl);
  } else {
    int e = (b - fifth - 1) * 256 + t;         // 0..799999 exactly
    rank[e] = atomicAdd(&cnt[dst[e]], 1);
  }
}

// ---- conv2 gemm: row-strip, A bf16 (loaded once, 8 n-tiles reuse) -------
__global__ __launch_bounds__(256) void gemm2_strip(const ushort* __restrict__ X,
                                                   const ushort* __restrict__ WT,
                                                   ushort* __restrict__ XW) {
  int strip = (blockIdx.x * 256 + threadIdx.x) >> 6;
  int lane = threadIdx.x & 63;
  if (strip >= N_NODES / 16) return;
  int m0 = strip * 16;
  int r = lane & 15, quad = lane >> 4;
  const ushort* xrow = X + (size_t)(m0 + r) * FEAT;
  short8 afr[4];
#pragma unroll
  for (int kb = 0; kb < 4; ++kb)
    afr[kb] = *(const short8*)(xrow + kb * 32 + quad * 8);
#pragma unroll
  for (int nt = 0; nt < 8; ++nt) {
    int n0 = nt * 16;
    floatx4 acc = {0.f, 0.f, 0.f, 0.f};
    const ushort* wrow = WT + (size_t)(n0 + r) * FEAT;
#pragma unroll
    for (int kb = 0; kb < 4; ++kb) {
      short8 b = *(const short8*)(wrow + kb * 32 + quad * 8);
      acc = __builtin_amdgcn_mfma_f32_16x16x32_bf16(afr[kb], b, acc, 0, 0, 0);
    }
#pragma unroll
    for (int reg = 0; reg < 4; ++reg)
      XW[(size_t)(m0 + quad * 4 + reg) * FEAT + n0 + r] = f2bf(acc[reg]);
  }
}

// ---- fused: dinv + graph counts + scan1 (all read cnt) ------------------
__global__ __launch_bounds__(256) void dinv_scan1(const int* __restrict__ cnt,
                                                  const int* __restrict__ batch,
                                                  float* __restrict__ dinv,
                                                  float* __restrict__ cnt_g,
                                                  int* __restrict__ ptr,
                                                  int* __restrict__ bsums) {
  __shared__ int tmp[256];
  __shared__ int bins[NGRAPH];
  if (threadIdx.x < NGRAPH) bins[threadIdx.x] = 0;
  int i = blockIdx.x * 256 + threadIdx.x;
  int v = (i < N_NODES) ? cnt[i] : 0;
  tmp[threadIdx.x] = v;
  __syncthreads();
  for (int off = 1; off < 256; off <<= 1) {
    int t = (threadIdx.x >= off) ? tmp[threadIdx.x - off] : 0;
    __syncthreads();
    tmp[threadIdx.x] += t;
    __syncthreads();
  }
  if (i < N_NODES) ptr[i] = tmp[threadIdx.x] - v;           // exclusive
  if (threadIdx.x == 255) bsums[blockIdx.x] = tmp[255];
  if (i < N_NODES) {
    dinv[i] = rsqrtf((float)v + 1.0f);
    atomicAdd(&bins[batch[i]], 1);
  }
  __syncthreads();
  if (threadIdx.x < NGRAPH && bins[threadIdx.x] > 0)
    atomicAdd(&cnt_g[threadIdx.x], (float)bins[threadIdx.x]);
}

__global__ __launch_bounds__(256) void scan2(int* __restrict__ bsums, int nb) {
  __shared__ int tmp[256];
  int v = (threadIdx.x < nb) ? bsums[threadIdx.x] : 0;
  tmp[threadIdx.x] = v;
  __syncthreads();
  for (int off = 1; off < 256; off <<= 1) {
    int t = (threadIdx.x >= off) ? tmp[threadIdx.x - off] : 0;
    __syncthreads();
    tmp[threadIdx.x] += t;
    __syncthreads();
  }
  if (threadIdx.x < nb) bsums[threadIdx.x] = tmp[threadIdx.x] - v;  // exclusive
}

__global__ __launch_bounds__(256) void scan3(int* __restrict__ ptr,
                                             const int* __restrict__ bsums) {
  int i = blockIdx.x * 256 + threadIdx.x;
  if (i < N_NODES) ptr[i] += bsums[blockIdx.x];
}

// ---- fill: atomic-free CSR scatter, payload {src, dinv[src]} ------------
__global__ __launch_bounds__(256) void fill_csr(const int* __restrict__ src,
                                                const int* __restrict__ dst,
                                                const int* __restrict__ rank,
                                                const int* __restrict__ ptr,
                                                const float* __restrict__ dinv,
                                                int2* __restrict__ edges) {
  int e = blockIdx.x * 256 + threadIdx.x;
  if (e >= N_EDGES) return;
  int s = src[e];
  edges[ptr[dst[e]] + rank[e]] = make_int2(s, __float_as_int(dinv[s]));
}

// ---- edge-gather accumulator (8-edge ILP) -------------------------------
static __device__ __forceinline__ float2 agg_node(const uint32_t* __restrict__ m32,
                                                  const int2* __restrict__ edges,
                                                  int start, int n, int lane) {
  float ax0 = 0.f, ay0 = 0.f, ax1 = 0.f, ay1 = 0.f;
  float ax2 = 0.f, ay2 = 0.f, ax3 = 0.f, ay3 = 0.f;
  int i = 0;
  if ((start & 1) && n > 0) {                   // align to int4 (2-edge) bound
    int2 e = edges[start];
    uint32_t u = m32[(size_t)e.x * 64 + lane];
    float nrm = __int_as_float(e.y);
    ax0 = fmaf(nrm, bfLo(u), ax0);
    ay0 = fmaf(nrm, bfHi(u), ay0);
    i = 1;
  }
  for (; i + 8 <= n; i += 8) {
    const int4* ep = (const int4*)(edges + start + i);   // 16B-aligned
    int4 q0 = ep[0], q1 = ep[1], q2 = ep[2], q3 = ep[3];
    uint32_t u0 = m32[(size_t)q0.x * 64 + lane];
    uint32_t u1 = m32[(size_t)q0.z * 64 + lane];
    uint32_t u2 = m32[(size_t)q1.x * 64 + lane];
    uint32_t u3 = m32[(size_t)q1.z * 64 + lane];
    uint32_t u4 = m32[(size_t)q2.x * 64 + lane];
    uint32_t u5 = m32[(size_t)q2.z * 64 + lane];
    uint32_t u6 = m32[(size_t)q3.x * 64 + lane];
    uint32_t u7 = m32[(size_t)q3.z * 64 + lane];
    float n0 = __int_as_float(q0.y), n1 = __int_as_float(q0.w);
    float n2 = __int_as_float(q1.y), n3 = __int_as_float(q1.w);
    float n4 = __int_as_float(q2.y), n5 = __int_as_float(q2.w);
    float n6 = __int_as_float(q3.y), n7 = __int_as_float(q3.w);
    ax0 = fmaf(n0, bfLo(u0), ax0); ay0 = fmaf(n0, bfHi(u0), ay0);
    ax1 = fmaf(n1, bfLo(u1), ax1); ay1 = fmaf(n1, bfHi(u1), ay1);
    ax2 = fmaf(n2, bfLo(u2), ax2); ay2 = fmaf(n2, bfHi(u2), ay2);
    ax3 = fmaf(n3, bfLo(u3), ax3); ay3 = fmaf(n3, bfHi(u3), ay3);
    ax0 = fmaf(n4, bfLo(u4), ax0); ay0 = fmaf(n4, bfHi(u4), ay0);
    ax1 = fmaf(n5, bfLo(u5), ax1); ay1 = fmaf(n5, bfHi(u5), ay1);
    ax2 = fmaf(n6, bfLo(u6), ax2); ay2 = fmaf(n6, bfHi(u6), ay2);
    ax3 = fmaf(n7, bfLo(u7), ax3); ay3 = fmaf(n7, bfHi(u7), ay3);
  }
  for (; i < n; ++i) {
    int2 e = edges[start + i];
    float nrm = __int_as_float(e.y);
    uint32_t u = m32[(size_t)e.x * 64 + lane];
    ax0 = fmaf(nrm, bfLo(u), ax0);
    ay0 = fmaf(nrm, bfHi(u), ay0);
  }
  return make_float2((ax0 + ax1) + (ax2 + ax3), (ay0 + ay1) + (ay2 + ay3));
}

// ---------------- aggregation (1 wave/node) ------------------------------
// MODE 0: out bf16 = relu(di*acc + b)   (conv1 -> h1, conv2 -> h2)
// MODE 2: out fp32 = di*acc             (conv3 pre-pool, no bias)
template <int MODE>
__global__ __launch_bounds__(256) void agg_kernel(const ushort* __restrict__ msg,
                                                  const float* __restrict__ dinv,
                                                  const int* __restrict__ ptr,
                                                  const int* __restrict__ cnt,
                                                  const int2* __restrict__ edges,
                                                  const float* __restrict__ bias,
                                                  void* __restrict__ outp) {
  int wave = (blockIdx.x * 256 + threadIdx.x) >> 6;
  int lane = threadIdx.x & 63;
  if (wave >= N_NODES) return;
  int v = wave;
  float di = dinv[v];
  const uint32_t* m32 = (const uint32_t*)msg;   // 64 dwords per node row
  uint32_t su = m32[(size_t)v * 64 + lane];     // self term, weight di
  float2 s = agg_node(m32, edges, ptr[v], cnt[v], lane);
  float ax = fmaf(di, bfLo(su), s.x);
  float ay = fmaf(di, bfHi(su), s.y);
  if (MODE == 2) {
    ((float2*)outp)[(size_t)v * 64 + lane] = make_float2(ax * di, ay * di);
  } else {
    ax = fmaf(ax, di, bias[2 * lane]);
    ay = fmaf(ay, di, bias[2 * lane + 1]);
    ushort2 h2;
    h2.x = f2bf(fmaxf(ax, 0.f));
    h2.y = f2bf(fmaxf(ay, 0.f));
    ((ushort2*)outp)[(size_t)v * 64 + lane] = h2;
  }
}

// ---------------- pool: segment-sum a3 over batch-sorted nodes -----------
__global__ __launch_bounds__(256) void pool_sum(const float* __restrict__ a3,
                                                const int* __restrict__ batch,
                                                float* __restrict__ P) {
  int wave = blockIdx.x * 4 + (threadIdx.x >> 6);
  int lane = threadIdx.x & 63;
  int v0 = wave * 16;
  if (v0 >= N_NODES) return;
  int vend = v0 + 16;
  if (vend > N_NODES) vend = N_NODES;
  const float2* a2 = (const float2*)a3;
  float ax = 0.f, ay = 0.f;
  int g = batch[v0];
  for (int v = v0; v < vend; ++v) {
    int gv = batch[v];
    if (gv != g) {
      atomicAdd(&P[(size_t)g * FEAT + 2 * lane], ax);
      atomicAdd(&P[(size_t)g * FEAT + 2 * lane + 1], ay);
      ax = 0.f; ay = 0.f; g = gv;
    }
    float2 t = a2[(size_t)v * 64 + lane];
    ax += t.x;
    ay += t.y;
  }
  atomicAdd(&P[(size_t)g * FEAT + 2 * lane], ax);
  atomicAdd(&P[(size_t)g * FEAT + 2 * lane + 1], ay);
}

// ---------------- per-layer FC head --------------------------------------
template <int K, int C, int KSLICE, int RELU_IN, int DIVC, int NSPLIT>
__global__ __launch_bounds__(256) void fc_layer(const float* __restrict__ IN,
                                                const float* __restrict__ W,
                                                const float* __restrict__ Bs,
                                                const float* __restrict__ cntg,
                                                float* __restrict__ OUT) {
  constexpr int CB = (C + 63) / 64;
  int lane = threadIdx.x & 63;
  int gq = threadIdx.x >> 6;
  int bid = blockIdx.x;
  int kp = bid % NSPLIT;
  int rest = bid / NSPLIT;
  int cg = rest % CB;
  int g = (rest / CB) * 4 + gq;
  int c = cg * 64 + lane;
  if (c >= C) return;
  int k0 = kp * KSLICE;
  const float* wp = W + (size_t)k0 * C + c;
  const float* in = IN + (size_t)g * K + k0;
  float cf = 1.f;
  if (DIVC) cf = fmaxf(cntg[g], 1.f);
  float a0 = 0.f, a1 = 0.f, a2 = 0.f, a3 = 0.f;
  float a4 = 0.f, a5 = 0.f, a6 = 0.f, a7 = 0.f;
#pragma unroll 2
  for (int k = 0; k < KSLICE; k += 8) {
    float i0 = in[k + 0], i1 = in[k + 1], i2 = in[k + 2], i3 = in[k + 3];
    float i4 = in[k + 4], i5 = in[k + 5], i6 = in[k + 6], i7 = in[k + 7];
    if (RELU_IN) {
      i0 = fmaxf(i0, 0.f); i1 = fmaxf(i1, 0.f);
      i2 = fmaxf(i2, 0.f); i3 = fmaxf(i3, 0.f);
      i4 = fmaxf(i4, 0.f); i5 = fmaxf(i5, 0.f);
      i6 = fmaxf(i6, 0.f); i7 = fmaxf(i7, 0.f);
    }
    if (DIVC) {
      i0 /= cf; i1 /= cf; i2 /= cf; i3 /= cf;
      i4 /= cf; i5 /= cf; i6 /= cf; i7 /= cf;
    }
    a0 = fmaf(i0, wp[(size_t)(k + 0) * C], a0);
    a1 = fmaf(i1, wp[(size_t)(k + 1) * C], a1);
    a2 = fmaf(i2, wp[(size_t)(k + 2) * C], a2);
    a3 = fmaf(i3, wp[(size_t)(k + 3) * C], a3);
    a4 = fmaf(i4, wp[(size_t)(k + 4) * C], a4);
    a5 = fmaf(i5, wp[(size_t)(k + 5) * C], a5);
    a6 = fmaf(i6, wp[(size_t)(k + 6) * C], a6);
    a7 = fmaf(i7, wp[(size_t)(k + 7) * C], a7);
  }
  float s = ((a0 + a1) + (a2 + a3)) + ((a4 + a5) + (a6 + a7));
  if (NSPLIT == 1) {
    OUT[(size_t)g * C + c] = s + Bs[c];
  } else {
    atomicAdd(&OUT[(size_t)g * C + c], s + (kp == 0 ? Bs[c] : 0.f));
  }
}

// =========================================================================
extern "C" void kernel_launch(void* const* d_in, const int* in_sizes, int n_in,
                              void* d_out, int out_size, void* d_ws, size_t ws_size,
                              hipStream_t stream) {
  const float* x         = (const float*)d_in[0];
  const int*   ei        = (const int*)d_in[1];     // [2][E]: row0 src, row1 dst
  const int*   batch     = (const int*)d_in[2];
  const float* conv_w[3] = {(const float*)d_in[3], (const float*)d_in[5], (const float*)d_in[7]};
  const float* conv_b[3] = {(const float*)d_in[4], (const float*)d_in[6], (const float*)d_in[8]};
  const float* fc_w[5]   = {(const float*)d_in[9],  (const float*)d_in[11],
                            (const float*)d_in[13], (const float*)d_in[15],
                            (const float*)d_in[17]};
  const float* fc_b[5]   = {(const float*)d_in[10], (const float*)d_in[12],
                            (const float*)d_in[14], (const float*)d_in[16],
                            (const float*)d_in[18]};
  const int* e_src = ei;
  const int* e_dst = ei + N_EDGES;
  float* out_f = (float*)d_out;                  // [64][128] fp32  (output 0)
  float* out_y = (float*)d_out + NGRAPH * FEAT;  // [64][10]  fp32  (output 1)

  char* p = (char*)d_ws;
  auto carve = [&](size_t bytes) {
    char* r = p;
    p += (bytes + 255) & ~(size_t)255;
    return r;
  };
  int*    cnt_i   = (int*)carve(N_NODES * 4);
  float*  dinv    = (float*)carve(N_NODES * 4);
  int*    csr_ptr = (int*)carve(N_NODES * 4);
  int*    bsums   = (int*)carve(256 * 4);
  int2*   edges   = (int2*)carve((size_t)N_EDGES * 8);            // {src, dinv_s}
  ushort* wbT     = (ushort*)carve((size_t)2 * FEAT * FEAT * 2);  // bf16 W^T conv1/2
  ushort* hbuf    = (ushort*)carve((size_t)N_NODES * FEAT * 2);   // bf16 h1 then h2
  float*  f_sum   = (float*)carve(NGRAPH * FEAT * 4);             // P
  float*  cnt_g   = (float*)carve(NGRAPH * 4);                    // adjacent to f_sum
  float*  Y1      = (float*)carve(NGRAPH * 1024 * 4);             // fc1 pre-act
  float*  Y2      = (float*)carve(NGRAPH * 512 * 4);              // fc2 pre-act (atomic)
  float*  Y3      = (float*)carve(NGRAPH * 256 * 4);              // fc3 pre-act (atomic)
  float*  Y4      = (float*)carve(NGRAPH * 128 * 4);              // fc4 pre-act (atomic)
  // Shared region (28.8 MB): [rank 3.2M][msl1 12.8M][msl2 12.8M].
  // Lifetimes: rank [gemm_rank..fill_csr]; msl1 [gemm_rank..agg1];
  // msl2 [gemm2_strip..agg2]. a3 (25.6M fp32) overlays the region start,
  // written by agg<2> when rank/msl1/msl2 are all dead. hbuf: h1
  // [agg1..gemm2_strip], then h2 [agg2..agg<2>] (h1 dead at overwrite).
  char*   region  = carve((size_t)N_EDGES * 4 + 2 * (size_t)N_NODES * FEAT * 2);
  int*    rank    = (int*)region;
  ushort* msl1    = (ushort*)(region + (size_t)N_EDGES * 4);
  ushort* msl2    = (ushort*)(region + (size_t)N_EDGES * 4 + (size_t)N_NODES * FEAT * 2);
  float*  a3      = (float*)region;

  const int BLK_N = (N_NODES + 255) / 256;   // 196

  // zero-init (ws + out are poisoned 0xAA each timed call)
  hipMemsetAsync(cnt_i, 0, N_NODES * 4, stream);
  hipMemsetAsync(f_sum, 0, NGRAPH * FEAT * 4 + 256, stream);      // f_sum + cnt_g
  hipMemsetAsync(Y2, 0, NGRAPH * (512 + 256 + 128) * 4, stream);  // atomic targets

  // ---- tiny weight transpose-cvt (feeds gemm_rank) ----
  wcvt<<<32, 256, 0, stream>>>(conv_w[0], conv_w[1], wbT);

  // ---- K1: conv1 row-strip gemm overlapped with rank atomics ----
  gemm_rank<<<GR_BLKS, 256, 0, stream>>>(x, wbT, msl1, e_dst, cnt_i, rank);

  // ---- dinv + graph counts + scan1 (1 dispatch) ----
  dinv_scan1<<<BLK_N, 256, 0, stream>>>(cnt_i, batch, dinv, cnt_g, csr_ptr, bsums);
  scan2<<<1, 256, 0, stream>>>(bsums, BLK_N);
  scan3<<<BLK_N, 256, 0, stream>>>(csr_ptr, bsums);

  // ---- atomic-free CSR fill ----
  fill_csr<<<E_BLKS, 256, 0, stream>>>(e_src, e_dst, rank, csr_ptr, dinv, edges);

  const int AGG_BLKS  = (N_NODES + 3) / 4;
  const int POOL_BLKS = (N_NODES / 16 + 3) / 4 + 1;

  // ---- conv1 agg: h1 = relu(di*acc + b1) ----
  agg_kernel<0><<<AGG_BLKS, 256, 0, stream>>>(msl1, dinv, csr_ptr, cnt_i, edges,
                                              conv_b[0], hbuf);
  // ---- conv2 gemm (row-strip, A once): msl2 = h1 @ W2 ----
  gemm2_strip<<<GSTRIP_BLKS, 256, 0, stream>>>(hbuf, wbT + FEAT * FEAT, msl2);
  // ---- conv2 agg: h2 = relu(di*acc + b2) ----
  agg_kernel<0><<<AGG_BLKS, 256, 0, stream>>>(msl2, dinv, csr_ptr, cnt_i, edges,
                                              conv_b[1], hbuf);
  // ---- conv3 pre-pool: a3 = di*acc(h2), fp32 ----
  agg_kernel<2><<<AGG_BLKS, 256, 0, stream>>>(hbuf, dinv, csr_ptr, cnt_i, edges,
                                              nullptr, a3);
  // ---- per-graph segment sum (batch sorted) ----
  pool_sum<<<POOL_BLKS, 256, 0, stream>>>(a3, batch, f_sum);

  // ---- per-layer head: Pn@W3 -> fc1..fc5 (stream-ordered) ----
  fc_layer< 128, 128, 128, 0, 1, 1><<< 32, 256, 0, stream>>>(f_sum, conv_w[2], conv_b[2], cnt_g, out_f);
  fc_layer< 128,1024, 128, 0, 0, 1><<<256, 256, 0, stream>>>(out_f, fc_w[0], fc_b[0], nullptr, Y1);
  fc_layer<1024, 512, 256, 1, 0, 4><<<512, 256, 0, stream>>>(Y1, fc_w[1], fc_b[1], nullptr, Y2);
  fc_layer< 512, 256, 128, 1, 0, 4><<<256, 256, 0, stream>>>(Y2, fc_w[2], fc_b[2], nullptr, Y3);
  fc_layer< 256, 128,  32, 1, 0, 8><<<256, 256, 0, stream>>>(Y3, fc_w[3], fc_b[3], nullptr, Y4);
  fc_layer< 128,  10, 128, 1, 0, 1><<< 16, 256, 0, stream>>>(Y4, fc_w[4], fc_b[4], nullptr, out_y);
}